// Round 5
// baseline (1292.194 us; speedup 1.0000x reference)
//
#include <hip/hip_runtime.h>
#include <hip/hip_bf16.h>
#include <math.h>

// Problem constants (from reference)
#define B_SZ   128
#define HDIM   256
#define NG     1280     // 5*H
#define NNODES 1023
#define VOCAB  2048

typedef unsigned int uint32;
typedef short  short8v  __attribute__((ext_vector_type(8)));   // 8 x bf16 (4 VGPR)
typedef float  float4v  __attribute__((ext_vector_type(4)));   // MFMA C/D frag

__device__ __forceinline__ float sigm(float x) {
    return 1.0f / (1.0f + __expf(-x));
}
__device__ __forceinline__ float tanh_fast(float x) {
    return 2.0f / (1.0f + __expf(-2.0f * x)) - 1.0f;
}
__device__ __forceinline__ float bf2f(unsigned short u) {
    return __uint_as_float(((uint32)u) << 16);
}
__device__ __forceinline__ unsigned short f2bf(float f) {
    uint32 x = __float_as_uint(f);
    uint32 r = (x + 0x7FFFu + ((x >> 16) & 1u)) >> 16;   // RNE
    return (unsigned short)r;
}

// Async 16B/lane global->LDS DMA. LDS dest = wave-uniform base + lane*16.
__device__ __forceinline__ void dma16(const unsigned short* gptr, unsigned short* lptr) {
    __builtin_amdgcn_global_load_lds(
        (const __attribute__((address_space(1))) void*)gptr,
        (__attribute__((address_space(3))) void*)lptr, 16, 0, 0);
}

// Device-scope grid barrier (all blocks co-resident by construction).
// Release fence -> arrive -> spin on generation -> acquire fence.
__device__ __forceinline__ void grid_barrier(unsigned* cnt, unsigned* gen, unsigned nb) {
    __threadfence();                 // release: my stores agent-visible (L2 wb)
    __syncthreads();
    if (threadIdx.x == 0) {
        unsigned g = __hip_atomic_load(gen, __ATOMIC_RELAXED, __HIP_MEMORY_SCOPE_AGENT);
        unsigned a = __hip_atomic_fetch_add(cnt, 1u, __ATOMIC_ACQ_REL, __HIP_MEMORY_SCOPE_AGENT);
        if (a == nb - 1u) {
            __hip_atomic_store(cnt, 0u, __ATOMIC_RELAXED, __HIP_MEMORY_SCOPE_AGENT);
            __hip_atomic_fetch_add(gen, 1u, __ATOMIC_RELEASE, __HIP_MEMORY_SCOPE_AGENT);
        } else {
            while (__hip_atomic_load(gen, __ATOMIC_ACQUIRE, __HIP_MEMORY_SCOPE_AGENT) == g)
                __builtin_amdgcn_s_sleep(2);
        }
    }
    __syncthreads();
    __threadfence();                 // acquire: invalidate stale L1/L2 before reads
}

// ---------------------------------------------------------------------------
// embb = bf16(emb) : 2048 x 256.  Also zero-inits the grid-barrier state.
// ---------------------------------------------------------------------------
__global__ __launch_bounds__(256) void embb_kernel(
    const float* __restrict__ emb, unsigned short* __restrict__ embb,
    unsigned* __restrict__ bar)
{
    const int t = blockIdx.x * 256 + threadIdx.x;
    if (t == 0) { bar[0] = 0u; bar[1] = 0u; }
    const float4 v0 = *(const float4*)(emb + (size_t)t * 8);
    const float4 v1 = *(const float4*)(emb + (size_t)t * 8 + 4);
    short8v o;
    o[0] = (short)f2bf(v0.x); o[1] = (short)f2bf(v0.y);
    o[2] = (short)f2bf(v0.z); o[3] = (short)f2bf(v0.w);
    o[4] = (short)f2bf(v1.x); o[5] = (short)f2bf(v1.y);
    o[6] = (short)f2bf(v1.z); o[7] = (short)f2bf(v1.w);
    *(short8v*)(embb + (size_t)t * 8) = o;
}

// ---------------------------------------------------------------------------
// WTf: fragment-ready bf16 repack of [Ul;Ur;Wx] (K=768, N=1280) for MFMA B.
// short8 index = (ng*24 + ks)*64 + lane ; lane = q*16 + c
//   holds B[k = ks*32 + q*8 + j][col = ng*16 + c],  j = 0..7
// Gather levels (d>=6) use ks 0..15 ([Ul;Ur]); fused tail uses all 24;
// the EW builder uses ks 16..23 (Wx).
// ---------------------------------------------------------------------------
__global__ __launch_bounds__(256) void prep_wtf(
    const float* __restrict__ Ul, const float* __restrict__ Ur,
    const float* __restrict__ Wx, unsigned short* __restrict__ WTf)
{
    const int t = blockIdx.x * 256 + threadIdx.x;   // 0..122879
    const int l = t & 63;
    const int q = l >> 4, c = l & 15;
    const int ks = (t >> 6) % 24;
    const int ng = t / (24 * 64);                    // 0..79
    const int col = ng * 16 + c;
    const int k = ks * 32 + q * 8;
    const float* src = (k < 256) ? (Ul + (size_t)k * NG + col)
                     : (k < 512) ? (Ur + (size_t)(k - 256) * NG + col)
                                 : (Wx + (size_t)(k - 512) * NG + col);
    short8v v;
    #pragma unroll
    for (int j = 0; j < 8; ++j) v[j] = (short)f2bf(src[(size_t)j * NG]);
    *(short8v*)(WTf + (size_t)t * 8) = v;
}

// ---------------------------------------------------------------------------
// EWb = bf16(embb @ Wx + b) via MFMA.  Consumed by leaftab and by the
// d>=6 gather levels' epilogues (bias already folded in).
// ---------------------------------------------------------------------------
__global__ __launch_bounds__(256, 2) void ewb_mfma(
    const unsigned short* __restrict__ WTf, const unsigned short* __restrict__ embb,
    const float* __restrict__ bias, unsigned short* __restrict__ EWb)
{
    __shared__ __align__(16) unsigned short Ab[2][4096];   // 16 KB A dbuf
    __shared__ __align__(16) unsigned short wbE[20480];    // 40 KB: 5 gates x 64 rows x 64 cols

    const int tid  = threadIdx.x;
    const int lane = tid & 63;
    const int w    = tid >> 6;                  // 0..3 = col-tile
    const int quad = lane >> 4, col15 = lane & 15;
    const int jt = blockIdx.x;
    const int rowBase = blockIdx.y * 64;        // emb row
    const int jbase   = jt * 64;

    const unsigned short* agp[2];
    unsigned short* ldst[2];
    #pragma unroll
    for (int t = 0; t < 2; ++t) {
        const int ch = 2 * w + t, sub = ch >> 2, rt = ch & 3;
        const int srow = rowBase + rt * 16 + col15;
        agp[t]  = embb + (size_t)srow * HDIM + sub * 32 + quad * 8;
        ldst[t] = &Ab[0][0] + ch * 512;
    }

    const short8v* WTfv = (const short8v*)WTf;
    uint32 boff[5];
    #pragma unroll
    for (int g = 0; g < 5; ++g)
        boff[g] = ((g * 16 + jt * 4 + w) * 24 + 16) * 64 + lane;   // Wx section

    float4v acc[4][5];
    #pragma unroll
    for (int rt = 0; rt < 4; ++rt)
        #pragma unroll
        for (int g = 0; g < 5; ++g)
            #pragma unroll
            for (int e = 0; e < 4; ++e) acc[rt][g][e] = 0.0f;

    dma16(agp[0], ldst[0]); dma16(agp[1], ldst[1]);
    __syncthreads();

    #pragma unroll
    for (int s = 0; s < 4; ++s) {
        if (s < 3) {
            dma16(agp[0] + (s + 1) * 64, ldst[0] + ((s + 1) & 1) * 4096);
            dma16(agp[1] + (s + 1) * 64, ldst[1] + ((s + 1) & 1) * 4096);
        }
        #pragma unroll
        for (int sub = 0; sub < 2; ++sub) {
            short8v bf[5];
            #pragma unroll
            for (int g = 0; g < 5; ++g) bf[g] = WTfv[boff[g] + (s * 2 + sub) * 64];
            #pragma unroll
            for (int rt = 0; rt < 4; ++rt) {
                const short8v af = *(const short8v*)&Ab[s & 1][(sub * 4 + rt) * 512 + lane * 8];
                #pragma unroll
                for (int g = 0; g < 5; ++g)
                    acc[rt][g] = __builtin_amdgcn_mfma_f32_16x16x32_bf16(
                        af, bf[g], acc[rt][g], 0, 0, 0);
            }
        }
        __syncthreads();
    }

    const int jl = w * 16 + col15;
    const int j  = jbase + jl;
    float bz[5];
    #pragma unroll
    for (int g = 0; g < 5; ++g) bz[g] = bias[g * 256 + j];
    const int jchunk = jl >> 3, jpos = jl & 7;

    #pragma unroll
    for (int rt = 0; rt < 4; ++rt) {
        #pragma unroll
        for (int reg = 0; reg < 4; ++reg) {
            const int rr = rt * 16 + quad * 4 + reg;
            const int roff = ((jchunk + 2 * quad) & 7) * 8 + jpos;  // (rr>>2)&3==quad
            #pragma unroll
            for (int g = 0; g < 5; ++g)
                wbE[(g * 64 + rr) * 64 + roff] = f2bf(acc[rt][g][reg] + bz[g]);
        }
    }
    __syncthreads();

    #pragma unroll
    for (int k2 = 0; k2 < 10; ++k2) {
        const int c = tid + k2 * 256;                // 0..2559
        const int g = c >> 9, rr = (c >> 3) & 63, u = c & 7;
        const int ru = (u + 2 * ((rr >> 2) & 3)) & 7;
        const short8v v = *(const short8v*)&wbE[(g * 64 + rr) * 64 + ru * 8];
        *(short8v*)(EWb + (size_t)(rowBase + rr) * NG + g * 256 + jbase + u * 8) = v;
    }
}

// ---------------------------------------------------------------------------
// Leaf-as-table: leaf h/c depend ONLY on the token.
// ---------------------------------------------------------------------------
__global__ __launch_bounds__(256) void leaftab_kernel(
    const unsigned short* __restrict__ EWb,
    unsigned short* __restrict__ Hleaf, unsigned short* __restrict__ Cleaf)
{
    const int t = blockIdx.x * 256 + threadIdx.x;   // 0..524287
    const int tok = t >> 8, j = t & 255;
    const float gi = bf2f(EWb[(size_t)tok * NG + j]);
    const float go = bf2f(EWb[(size_t)tok * NG + 768 + j]);
    const float gu = bf2f(EWb[(size_t)tok * NG + 1024 + j]);
    const float c = sigm(gi) * tanh_fast(gu);
    const float h = sigm(go) * tanh_fast(c);
    Hleaf[t] = f2bf(h);
    Cleaf[t] = f2bf(c);
}

// ---------------------------------------------------------------------------
// Big levels d>=6 (grids >=512 blocks): K=512 GEMM [hl|hr]@[Ul;Ur] (BK=128,
// 4 steps) + EW-gather epilogue (EWb row per node token; bias already in).
// R20 rationale: R2 vs R3/R4 showed the EW epilogue gather is FREE at big
// grids (parallelism hides it) while K-extension costs ~linear -> gather
// beats fold for d>=6.  Fold stays for the fused tail (latency regime).
// ---------------------------------------------------------------------------
template <bool LEAF>
__global__ __launch_bounds__(256, 2) void level_gather(
    const unsigned short* __restrict__ WTf, const int* __restrict__ tokens,
    const unsigned short* __restrict__ EWb,
    const unsigned short* __restrict__ Hleaf, const unsigned short* __restrict__ Cleaf,
    const unsigned short* __restrict__ hsrc, const unsigned short* __restrict__ csrc,
    unsigned short* __restrict__ hdst, unsigned short* __restrict__ cdst,
    const int d)
{
    const int n = 1 << d;

    __shared__ __align__(16) unsigned short Ab[2][8192];   // 32 KB: dbuf 64r x 128k

    const int tid  = threadIdx.x;
    const int lane = tid & 63;
    const int w    = tid >> 6;                  // 0..3 = col-tile AND k-sub
    const int quad = lane >> 4, col15 = lane & 15;
    const int jt = blockIdx.x;                  // 0..3 (fastest)
    const int rowBase = blockIdx.y * 64;
    const int jbase   = jt * 64;

    // A staging: 16 chunks/step (sub 0..3 = k-32-block, rt 0..3 = row-16-blk);
    // wave w stages sub=w.  Byte offsets vs base pointers (register thrift).
    const uint32 inrow = (uint32)(w * 64 + quad * 16);
    uint32 oL[4], oR[4];
    #pragma unroll
    for (int t = 0; t < 4; ++t) {
        const int srow = rowBase + t * 16 + col15;
        if (LEAF) {
            const int b = srow >> 8, i = srow & 255;
            oL[t] = (uint32)tokens[b * NNODES + 511 + 2 * i] * 512u + inrow;
            oR[t] = (uint32)tokens[b * NNODES + 512 + 2 * i] * 512u + inrow;
        } else {
            oL[t] = (uint32)(2 * srow) * 512u + inrow;
            oR[t] = oL[t] + 512u;
        }
    }
    const char* hb = LEAF ? (const char*)Hleaf : (const char*)hsrc;

    const short8v* WTfv = (const short8v*)WTf;
    uint32 boff[5];
    #pragma unroll
    for (int g = 0; g < 5; ++g)
        boff[g] = ((g * 16 + jt * 4 + w) * 24) * 64 + lane;   // [Ul;Ur]: ks 0..15

    float4v acc[4][5];
    #pragma unroll
    for (int rt = 0; rt < 4; ++rt)
        #pragma unroll
        for (int g = 0; g < 5; ++g)
            #pragma unroll
            for (int e = 0; e < 4; ++e) acc[rt][g][e] = 0.0f;

    {
        unsigned short* dst = &Ab[0][0] + w * 2048;
        #pragma unroll
        for (int t = 0; t < 4; ++t)
            dma16((const unsigned short*)(hb + oL[t]), dst + t * 512);
    }
    __syncthreads();

    #pragma unroll
    for (int s = 0; s < 4; ++s) {
        if (s < 3) {
            const int sn = s + 1;
            unsigned short* dst = &Ab[sn & 1][0] + w * 2048;
            #pragma unroll
            for (int t = 0; t < 4; ++t) {
                const char* p = (sn < 2) ? (hb + oL[t] + sn * 256)
                                         : (hb + oR[t] + (sn - 2) * 256);
                dma16((const unsigned short*)p, dst + t * 512);
            }
        }
        #pragma unroll
        for (int sub = 0; sub < 4; ++sub) {
            short8v bf[5];
            #pragma unroll
            for (int g = 0; g < 5; ++g) bf[g] = WTfv[boff[g] + (s * 4 + sub) * 64];
            #pragma unroll
            for (int rt = 0; rt < 4; ++rt) {
                const short8v af = *(const short8v*)&Ab[s & 1][(sub * 4 + rt) * 512 + lane * 8];
                #pragma unroll
                for (int g = 0; g < 5; ++g)
                    acc[rt][g] = __builtin_amdgcn_mfma_f32_16x16x32_bf16(
                        af, bf[g], acc[rt][g], 0, 0, 0);
            }
        }
        __syncthreads();
    }

    // ---- Epilogue: EW gates gathered from EWb[token] (bias included), child
    // c gathered direct.  C layout: col=lane&15, row=quad*4+reg.
    const int jl = w * 16 + col15;
    const int j  = jbase + jl;
    float hv[4][4], cv[4][4];
    #pragma unroll
    for (int rt = 0; rt < 4; ++rt) {
        #pragma unroll
        for (int reg = 0; reg < 4; ++reg) {
            const int rr = rt * 16 + quad * 4 + reg;
            const int grow = rowBase + rr;
            const int tok = tokens[(grow >> d) * NNODES + (n - 1) + (grow & (n - 1))];
            const unsigned short* ewp = EWb + (size_t)tok * NG + j;
            float cl, cr;
            if (LEAF) {
                const int b = grow >> 8, i = grow & 255;
                const int tokL = tokens[b * NNODES + 511 + 2 * i];
                const int tokR = tokens[b * NNODES + 512 + 2 * i];
                cl = bf2f(Cleaf[(size_t)tokL * HDIM + j]);
                cr = bf2f(Cleaf[(size_t)tokR * HDIM + j]);
            } else {
                cl = bf2f(csrc[(size_t)(2 * grow) * HDIM + j]);
                cr = bf2f(csrc[(size_t)(2 * grow + 1) * HDIM + j]);
            }
            const float gi  = acc[rt][0][reg] + bf2f(ewp[0]);
            const float gfl = acc[rt][1][reg] + bf2f(ewp[256]);
            const float gfr = acc[rt][2][reg] + bf2f(ewp[512]);
            const float go  = acc[rt][3][reg] + bf2f(ewp[768]);
            const float gu  = acc[rt][4][reg] + bf2f(ewp[1024]);
            const float ii = sigm(gi), fl = sigm(gfl), fr = sigm(gfr), oo = sigm(go);
            const float uu = tanh_fast(gu);
            const float c = ii * uu + fl * cl + fr * cr;
            const float h = oo * tanh_fast(c);
            cv[rt][reg] = c; hv[rt][reg] = h;
        }
    }

    // ---- Writeback via swizzled staging; Ab is dead past the last barrier.
    unsigned short* wb = &Ab[0][0];
    const int jchunk = jl >> 3, jpos = jl & 7;
    __syncthreads();
    #pragma unroll
    for (int rt = 0; rt < 4; ++rt) {
        #pragma unroll
        for (int reg = 0; reg < 4; ++reg) {
            const int rr = rt * 16 + quad * 4 + reg;
            const int roff = ((jchunk + 2 * quad) & 7) * 8 + jpos;
            wb[rr * 64 + roff]        = f2bf(hv[rt][reg]);
            wb[4096 + rr * 64 + roff] = f2bf(cv[rt][reg]);
        }
    }
    __syncthreads();
    #pragma unroll
    for (int k2 = 0; k2 < 4; ++k2) {
        const int c = tid + k2 * 256;
        const int arr = c >> 9, rr = (c >> 3) & 63, u = c & 7;
        const int ru = (u + 2 * ((rr >> 2) & 3)) & 7;
        const short8v v = *(const short8v*)(wb + (arr * 4096 + rr * 64 + ru * 8));
        unsigned short* dstp = (arr ? cdst : hdst) +
            (size_t)(rowBase + rr) * HDIM + jbase + u * 8;
        *(short8v*)dstp = v;
    }
}

// ---------------------------------------------------------------------------
// Fused tail: levels d=5..0 in ONE persistent kernel, grid-barrier between
// levels.  Grid = 256 blocks x 256 thr, 32 KB LDS, (256,2) -> co-residency
// guaranteed (1 block/CU needed, >=2 fit).  Body = R4's K=768 fold (the
// latency-optimal variant: no epilogue EW gather on the critical path).
// Replaces 6 launches + their ~10us/level low-occupancy latency floors.
// ---------------------------------------------------------------------------
__global__ __launch_bounds__(256, 2) void level_fused(
    const unsigned short* __restrict__ WTf, const int* __restrict__ tokens,
    const unsigned short* __restrict__ embb,
    unsigned short* __restrict__ hA, unsigned short* __restrict__ cA,
    unsigned short* __restrict__ hB, unsigned short* __restrict__ cB,
    const float* __restrict__ bias, float* __restrict__ out,
    unsigned* __restrict__ bar)
{
    __shared__ __align__(16) unsigned short Ab[2][8192];   // 32 KB

    const int tid  = threadIdx.x;
    const int lane = tid & 63;
    const int w    = tid >> 6;
    const int quad = lane >> 4, col15 = lane & 15;
    const int bid  = blockIdx.x;
    const int jt   = bid & 3;
    const int jbase = jt * 64;
    const int jl = w * 16 + col15;
    const int j  = jbase + jl;
    const uint32 inrow = (uint32)(w * 64 + quad * 16);

    float bz[5];
    #pragma unroll
    for (int g = 0; g < 5; ++g) bz[g] = bias[g * 256 + j];

    const short8v* WTfv = (const short8v*)WTf;
    uint32 boff[5];
    #pragma unroll
    for (int g = 0; g < 5; ++g)
        boff[g] = ((g * 16 + jt * 4 + w) * 24) * 64 + lane;   // full K=768

    const char* xb = (const char*)embb;

    #pragma unroll 1
    for (int d = 5; d >= 0; --d) {
        const unsigned short *hsv, *csv;
        unsigned short *hdv, *cdv;
        if (d & 1) { hsv = hB; csv = cB; hdv = hA; cdv = cA; }
        else       { hsv = hA; csv = cA; hdv = hB; cdv = cB; }
        const int n = 1 << d;
        const int nact = 8 << d;                // 4 * 2^(d+1) active blocks

        if (bid < nact) {
            const int rowBase = (bid >> 2) * 64;

            uint32 oL[4], oR[4], oN[4];
            #pragma unroll
            for (int t = 0; t < 4; ++t) {
                const int srow = rowBase + t * 16 + col15;
                const int b = srow >> d, i = srow & (n - 1);
                oN[t] = (uint32)tokens[b * NNODES + (n - 1) + i] * 512u + inrow;
                oL[t] = (uint32)(2 * srow) * 512u + inrow;
                oR[t] = oL[t] + 512u;
            }
            const char* hb = (const char*)hsv;

            float4v acc[4][5];
            #pragma unroll
            for (int rt = 0; rt < 4; ++rt)
                #pragma unroll
                for (int g = 0; g < 5; ++g)
                    #pragma unroll
                    for (int e = 0; e < 4; ++e) acc[rt][g][e] = 0.0f;

            {
                unsigned short* dst = &Ab[0][0] + w * 2048;
                #pragma unroll
                for (int t = 0; t < 4; ++t)
                    dma16((const unsigned short*)(hb + oL[t]), dst + t * 512);
            }
            __syncthreads();

            #pragma unroll
            for (int s = 0; s < 6; ++s) {
                if (s < 5) {
                    const int sn = s + 1;
                    unsigned short* dst = &Ab[sn & 1][0] + w * 2048;
                    #pragma unroll
                    for (int t = 0; t < 4; ++t) {
                        const char* p = (sn < 2) ? (hb + oL[t] + sn * 256)
                                      : (sn < 4) ? (hb + oR[t] + (sn - 2) * 256)
                                                 : (xb + oN[t] + (sn - 4) * 256);
                        dma16((const unsigned short*)p, dst + t * 512);
                    }
                }
                #pragma unroll
                for (int sub = 0; sub < 4; ++sub) {
                    short8v bf[5];
                    #pragma unroll
                    for (int g = 0; g < 5; ++g) bf[g] = WTfv[boff[g] + (s * 4 + sub) * 64];
                    #pragma unroll
                    for (int rt = 0; rt < 4; ++rt) {
                        const short8v af = *(const short8v*)&Ab[s & 1][(sub * 4 + rt) * 512 + lane * 8];
                        #pragma unroll
                        for (int g = 0; g < 5; ++g)
                            acc[rt][g] = __builtin_amdgcn_mfma_f32_16x16x32_bf16(
                                af, bf[g], acc[rt][g], 0, 0, 0);
                    }
                }
                __syncthreads();
            }

            float hv[4][4], cv[4][4];
            #pragma unroll
            for (int rt = 0; rt < 4; ++rt) {
                #pragma unroll
                for (int reg = 0; reg < 4; ++reg) {
                    const int rr = rt * 16 + quad * 4 + reg;
                    const int grow = rowBase + rr;
                    const float cl = bf2f(csv[(size_t)(2 * grow) * HDIM + j]);
                    const float cr = bf2f(csv[(size_t)(2 * grow + 1) * HDIM + j]);
                    const float gi  = acc[rt][0][reg] + bz[0];
                    const float gfl = acc[rt][1][reg] + bz[1];
                    const float gfr = acc[rt][2][reg] + bz[2];
                    const float go  = acc[rt][3][reg] + bz[3];
                    const float gu  = acc[rt][4][reg] + bz[4];
                    const float ii = sigm(gi), fl = sigm(gfl), fr = sigm(gfr), oo = sigm(go);
                    const float uu = tanh_fast(gu);
                    const float c = ii * uu + fl * cl + fr * cr;
                    const float h = oo * tanh_fast(c);
                    cv[rt][reg] = c; hv[rt][reg] = h;
                    if (d == 0) out[(size_t)grow * HDIM + j] = h;  // n==1 -> b=row
                }
            }

            if (d > 0) {
                unsigned short* wb = &Ab[0][0];
                const int jchunk = jl >> 3, jpos = jl & 7;
                #pragma unroll
                for (int rt = 0; rt < 4; ++rt) {
                    #pragma unroll
                    for (int reg = 0; reg < 4; ++reg) {
                        const int rr = rt * 16 + quad * 4 + reg;
                        const int roff = ((jchunk + 2 * quad) & 7) * 8 + jpos;
                        wb[rr * 64 + roff]        = f2bf(hv[rt][reg]);
                        wb[4096 + rr * 64 + roff] = f2bf(cv[rt][reg]);
                    }
                }
                __syncthreads();
                #pragma unroll
                for (int k2 = 0; k2 < 4; ++k2) {
                    const int c = tid + k2 * 256;
                    const int arr = c >> 9, rr = (c >> 3) & 63, u = c & 7;
                    const int ru = (u + 2 * ((rr >> 2) & 3)) & 7;
                    const short8v v = *(const short8v*)(wb + (arr * 4096 + rr * 64 + ru * 8));
                    unsigned short* dstp = (arr ? cdv : hdv) +
                        (size_t)(rowBase + rr) * HDIM + jbase + u * 8;
                    *(short8v*)dstp = v;
                }
            }
        }

        if (d > 0) grid_barrier(bar, bar + 1, gridDim.x);
    }
}

// ---------------------------------------------------------------------------
extern "C" void kernel_launch(void* const* d_in, const int* in_sizes, int n_in,
                              void* d_out, int out_size, void* d_ws, size_t ws_size,
                              hipStream_t stream)
{
    const int*   tokens = (const int*)d_in[0];
    const float* emb    = (const float*)d_in[1];
    const float* Wx     = (const float*)d_in[2];
    const float* Ul     = (const float*)d_in[3];
    const float* Ur     = (const float*)d_in[4];
    const float* bias   = (const float*)d_in[5];
    float* out = (float*)d_out;

    // Workspace (bf16): EWb 5.24 | embb 1.05 | WTf 1.97 | Hleaf+Cleaf 2.1 |
    // hA,cA 2x8.4 | hB,cB 2x16.8 | barrier 64B  -> ~61 MB total.
    const size_t EW_ELEMS  = (size_t)VOCAB * NG;
    const size_t EMB_ELEMS = (size_t)VOCAB * HDIM;
    const size_t WTF_ELEMS = (size_t)80 * 24 * 64 * 8;
    const size_t LT_ELEMS  = (size_t)VOCAB * HDIM;        // each of Hleaf, Cleaf
    const size_t SLOT_A    = (size_t)16384 * HDIM;        // d=7,5,3,1 outputs
    const size_t SLOT_B    = (size_t)32768 * HDIM;        // d=8,6,4,2,0 outputs
    const size_t REQUIRED  = (EW_ELEMS + EMB_ELEMS + WTF_ELEMS + 2 * LT_ELEMS
                              + 2 * (SLOT_A + SLOT_B)) * 2 + 64;
    if (ws_size < REQUIRED || d_ws == nullptr) return;   // clean fail, not a fault

    char* ws = (char*)d_ws;
    unsigned short* EWb   = (unsigned short*)ws;
    unsigned short* embb  = EWb + EW_ELEMS;
    unsigned short* WTf   = embb + EMB_ELEMS;
    unsigned short* Hleaf = WTf + WTF_ELEMS;
    unsigned short* Cleaf = Hleaf + LT_ELEMS;
    unsigned short* hA    = Cleaf + LT_ELEMS;
    unsigned short* cA    = hA + SLOT_A;
    unsigned short* hB    = cA + SLOT_A;
    unsigned short* cB    = hB + SLOT_B;
    unsigned* bar         = (unsigned*)(cB + SLOT_B);

    embb_kernel<<<dim3(256), 256, 0, stream>>>(emb, embb, bar);
    prep_wtf<<<dim3(480), 256, 0, stream>>>(Ul, Ur, Wx, WTf);
    ewb_mfma<<<dim3(4, 32), 256, 0, stream>>>(WTf, embb, bias, EWb);
    leaftab_kernel<<<dim3(2048), 256, 0, stream>>>(EWb, Hleaf, Cleaf);

    // Big levels: d=8 (leaf children via tables), d=7, d=6 — gather variant.
    // Ping-pong mapping: even d writes B-slot, odd d writes A-slot.
    level_gather<true><<<dim3(4, 512), 256, 0, stream>>>(
        WTf, tokens, EWb, Hleaf, Cleaf, nullptr, nullptr, hB, cB, 8);
    level_gather<false><<<dim3(4, 256), 256, 0, stream>>>(
        WTf, tokens, EWb, Hleaf, Cleaf, hB, cB, hA, cA, 7);
    level_gather<false><<<dim3(4, 128), 256, 0, stream>>>(
        WTf, tokens, EWb, Hleaf, Cleaf, hA, cA, hB, cB, 6);

    // Fused tail d=5..0 (persistent, grid-barrier between levels).
    level_fused<<<dim3(256), 256, 0, stream>>>(
        WTf, tokens, embb, hA, cA, hB, cB, bias, out, bar);
}

// Round 7
// 349.132 us; speedup vs baseline: 3.7012x; 3.7012x over previous
//
#include <hip/hip_runtime.h>
#include <hip/hip_bf16.h>
#include <math.h>

// Problem constants (from reference)
#define B_SZ   128
#define HDIM   256
#define NG     1280     // 5*H
#define NNODES 1023
#define VOCAB  2048

typedef unsigned int uint32;
typedef short  short8v  __attribute__((ext_vector_type(8)));   // 8 x bf16 (4 VGPR)
typedef float  float4v  __attribute__((ext_vector_type(4)));   // MFMA C/D frag

__device__ __forceinline__ float sigm(float x) {
    return 1.0f / (1.0f + __expf(-x));
}
__device__ __forceinline__ float tanh_fast(float x) {
    return 2.0f / (1.0f + __expf(-2.0f * x)) - 1.0f;
}
__device__ __forceinline__ float bf2f(unsigned short u) {
    return __uint_as_float(((uint32)u) << 16);
}
__device__ __forceinline__ unsigned short f2bf(float f) {
    uint32 x = __float_as_uint(f);
    uint32 r = (x + 0x7FFFu + ((x >> 16) & 1u)) >> 16;   // RNE
    return (unsigned short)r;
}

// Async 16B/lane global->LDS DMA. LDS dest = wave-uniform base + lane*16.
__device__ __forceinline__ void dma16(const unsigned short* gptr, unsigned short* lptr) {
    __builtin_amdgcn_global_load_lds(
        (const __attribute__((address_space(1))) void*)gptr,
        (__attribute__((address_space(3))) void*)lptr, 16, 0, 0);
}

// ---------------------------------------------------------------------------
// embb = bf16(emb) : 2048 x 256.  A-operand for the EW builder + levels' x.
// ---------------------------------------------------------------------------
__global__ __launch_bounds__(256) void embb_kernel(
    const float* __restrict__ emb, unsigned short* __restrict__ embb)
{
    const int t = blockIdx.x * 256 + threadIdx.x;
    const float4 v0 = *(const float4*)(emb + (size_t)t * 8);
    const float4 v1 = *(const float4*)(emb + (size_t)t * 8 + 4);
    short8v o;
    o[0] = (short)f2bf(v0.x); o[1] = (short)f2bf(v0.y);
    o[2] = (short)f2bf(v0.z); o[3] = (short)f2bf(v0.w);
    o[4] = (short)f2bf(v1.x); o[5] = (short)f2bf(v1.y);
    o[6] = (short)f2bf(v1.z); o[7] = (short)f2bf(v1.w);
    *(short8v*)(embb + (size_t)t * 8) = o;
}

// ---------------------------------------------------------------------------
// WTf: fragment-ready bf16 repack of [Ul;Ur;Wx] (K=768, N=1280) for MFMA B.
// short8 index = (ng*24 + ks)*64 + lane ; lane = q*16 + c
//   holds B[k = ks*32 + q*8 + j][col = ng*16 + c],  j = 0..7
// Gather levels (d>=6) use ks 0..15 ([Ul;Ur]); fold tail uses all 24;
// the EW builder uses ks 16..23 (Wx).
// ---------------------------------------------------------------------------
__global__ __launch_bounds__(256) void prep_wtf(
    const float* __restrict__ Ul, const float* __restrict__ Ur,
    const float* __restrict__ Wx, unsigned short* __restrict__ WTf)
{
    const int t = blockIdx.x * 256 + threadIdx.x;   // 0..122879
    const int l = t & 63;
    const int q = l >> 4, c = l & 15;
    const int ks = (t >> 6) % 24;
    const int ng = t / (24 * 64);                    // 0..79
    const int col = ng * 16 + c;
    const int k = ks * 32 + q * 8;
    const float* src = (k < 256) ? (Ul + (size_t)k * NG + col)
                     : (k < 512) ? (Ur + (size_t)(k - 256) * NG + col)
                                 : (Wx + (size_t)(k - 512) * NG + col);
    short8v v;
    #pragma unroll
    for (int j = 0; j < 8; ++j) v[j] = (short)f2bf(src[(size_t)j * NG]);
    *(short8v*)(WTf + (size_t)t * 8) = v;
}

// ---------------------------------------------------------------------------
// EWb = bf16(embb @ Wx + b) via MFMA.  Consumed by leaftab and the d>=6
// gather levels' epilogues (bias already folded in).
// ---------------------------------------------------------------------------
__global__ __launch_bounds__(256, 2) void ewb_mfma(
    const unsigned short* __restrict__ WTf, const unsigned short* __restrict__ embb,
    const float* __restrict__ bias, unsigned short* __restrict__ EWb)
{
    __shared__ __align__(16) unsigned short Ab[2][4096];   // 16 KB A dbuf
    __shared__ __align__(16) unsigned short wbE[20480];    // 40 KB: 5 gates x 64 rows x 64 cols

    const int tid  = threadIdx.x;
    const int lane = tid & 63;
    const int w    = tid >> 6;                  // 0..3 = col-tile
    const int quad = lane >> 4, col15 = lane & 15;
    const int jt = blockIdx.x;
    const int rowBase = blockIdx.y * 64;        // emb row
    const int jbase   = jt * 64;

    const unsigned short* agp[2];
    unsigned short* ldst[2];
    #pragma unroll
    for (int t = 0; t < 2; ++t) {
        const int ch = 2 * w + t, sub = ch >> 2, rt = ch & 3;
        const int srow = rowBase + rt * 16 + col15;
        agp[t]  = embb + (size_t)srow * HDIM + sub * 32 + quad * 8;
        ldst[t] = &Ab[0][0] + ch * 512;
    }

    const short8v* WTfv = (const short8v*)WTf;
    uint32 boff[5];
    #pragma unroll
    for (int g = 0; g < 5; ++g)
        boff[g] = ((g * 16 + jt * 4 + w) * 24 + 16) * 64 + lane;   // Wx section

    float4v acc[4][5];
    #pragma unroll
    for (int rt = 0; rt < 4; ++rt)
        #pragma unroll
        for (int g = 0; g < 5; ++g)
            #pragma unroll
            for (int e = 0; e < 4; ++e) acc[rt][g][e] = 0.0f;

    dma16(agp[0], ldst[0]); dma16(agp[1], ldst[1]);
    __syncthreads();

    #pragma unroll
    for (int s = 0; s < 4; ++s) {
        if (s < 3) {
            dma16(agp[0] + (s + 1) * 64, ldst[0] + ((s + 1) & 1) * 4096);
            dma16(agp[1] + (s + 1) * 64, ldst[1] + ((s + 1) & 1) * 4096);
        }
        #pragma unroll
        for (int sub = 0; sub < 2; ++sub) {
            short8v bf[5];
            #pragma unroll
            for (int g = 0; g < 5; ++g) bf[g] = WTfv[boff[g] + (s * 2 + sub) * 64];
            #pragma unroll
            for (int rt = 0; rt < 4; ++rt) {
                const short8v af = *(const short8v*)&Ab[s & 1][(sub * 4 + rt) * 512 + lane * 8];
                #pragma unroll
                for (int g = 0; g < 5; ++g)
                    acc[rt][g] = __builtin_amdgcn_mfma_f32_16x16x32_bf16(
                        af, bf[g], acc[rt][g], 0, 0, 0);
            }
        }
        __syncthreads();
    }

    const int jl = w * 16 + col15;
    const int j  = jbase + jl;
    float bz[5];
    #pragma unroll
    for (int g = 0; g < 5; ++g) bz[g] = bias[g * 256 + j];
    const int jchunk = jl >> 3, jpos = jl & 7;

    #pragma unroll
    for (int rt = 0; rt < 4; ++rt) {
        #pragma unroll
        for (int reg = 0; reg < 4; ++reg) {
            const int rr = rt * 16 + quad * 4 + reg;
            const int roff = ((jchunk + 2 * quad) & 7) * 8 + jpos;  // (rr>>2)&3==quad
            #pragma unroll
            for (int g = 0; g < 5; ++g)
                wbE[(g * 64 + rr) * 64 + roff] = f2bf(acc[rt][g][reg] + bz[g]);
        }
    }
    __syncthreads();

    #pragma unroll
    for (int k2 = 0; k2 < 10; ++k2) {
        const int c = tid + k2 * 256;                // 0..2559
        const int g = c >> 9, rr = (c >> 3) & 63, u = c & 7;
        const int ru = (u + 2 * ((rr >> 2) & 3)) & 7;
        const short8v v = *(const short8v*)&wbE[(g * 64 + rr) * 64 + ru * 8];
        *(short8v*)(EWb + (size_t)(rowBase + rr) * NG + g * 256 + jbase + u * 8) = v;
    }
}

// ---------------------------------------------------------------------------
// Leaf-as-table: leaf h/c depend ONLY on the token.
// ---------------------------------------------------------------------------
__global__ __launch_bounds__(256) void leaftab_kernel(
    const unsigned short* __restrict__ EWb,
    unsigned short* __restrict__ Hleaf, unsigned short* __restrict__ Cleaf)
{
    const int t = blockIdx.x * 256 + threadIdx.x;   // 0..524287
    const int tok = t >> 8, j = t & 255;
    const float gi = bf2f(EWb[(size_t)tok * NG + j]);
    const float go = bf2f(EWb[(size_t)tok * NG + 768 + j]);
    const float gu = bf2f(EWb[(size_t)tok * NG + 1024 + j]);
    const float c = sigm(gi) * tanh_fast(gu);
    const float h = sigm(go) * tanh_fast(c);
    Hleaf[t] = f2bf(h);
    Cleaf[t] = f2bf(c);
}

// ---------------------------------------------------------------------------
// Big levels d>=6 (grids >=512 blocks): K=512 GEMM [hl|hr]@[Ul;Ur] (BK=128,
// 4 steps) + EW-gather epilogue (EWb row per node token; bias already in).
// R2 vs R3/R4: the EW gather is hidden by TLP at big grids while K-extension
// costs ~linearly -> gather wins for d>=6.  Verified correct in R5.
// ---------------------------------------------------------------------------
template <bool LEAF>
__global__ __launch_bounds__(256, 2) void level_gather(
    const unsigned short* __restrict__ WTf, const int* __restrict__ tokens,
    const unsigned short* __restrict__ EWb,
    const unsigned short* __restrict__ Hleaf, const unsigned short* __restrict__ Cleaf,
    const unsigned short* __restrict__ hsrc, const unsigned short* __restrict__ csrc,
    unsigned short* __restrict__ hdst, unsigned short* __restrict__ cdst,
    const int d)
{
    const int n = 1 << d;

    __shared__ __align__(16) unsigned short Ab[2][8192];   // 32 KB: dbuf 64r x 128k

    const int tid  = threadIdx.x;
    const int lane = tid & 63;
    const int w    = tid >> 6;                  // 0..3 = col-tile AND k-sub
    const int quad = lane >> 4, col15 = lane & 15;
    const int jt = blockIdx.x;                  // 0..3 (fastest)
    const int rowBase = blockIdx.y * 64;
    const int jbase   = jt * 64;

    // A staging: 16 chunks/step (sub 0..3 = k-32-block, rt 0..3 = row-16-blk);
    // wave w stages sub=w.  Byte offsets vs base pointers (register thrift).
    const uint32 inrow = (uint32)(w * 64 + quad * 16);
    uint32 oL[4], oR[4];
    #pragma unroll
    for (int t = 0; t < 4; ++t) {
        const int srow = rowBase + t * 16 + col15;
        if (LEAF) {
            const int b = srow >> 8, i = srow & 255;
            oL[t] = (uint32)tokens[b * NNODES + 511 + 2 * i] * 512u + inrow;
            oR[t] = (uint32)tokens[b * NNODES + 512 + 2 * i] * 512u + inrow;
        } else {
            oL[t] = (uint32)(2 * srow) * 512u + inrow;
            oR[t] = oL[t] + 512u;
        }
    }
    const char* hb = LEAF ? (const char*)Hleaf : (const char*)hsrc;

    const short8v* WTfv = (const short8v*)WTf;
    uint32 boff[5];
    #pragma unroll
    for (int g = 0; g < 5; ++g)
        boff[g] = ((g * 16 + jt * 4 + w) * 24) * 64 + lane;   // [Ul;Ur]: ks 0..15

    float4v acc[4][5];
    #pragma unroll
    for (int rt = 0; rt < 4; ++rt)
        #pragma unroll
        for (int g = 0; g < 5; ++g)
            #pragma unroll
            for (int e = 0; e < 4; ++e) acc[rt][g][e] = 0.0f;

    {
        unsigned short* dst = &Ab[0][0] + w * 2048;
        #pragma unroll
        for (int t = 0; t < 4; ++t)
            dma16((const unsigned short*)(hb + oL[t]), dst + t * 512);
    }
    __syncthreads();

    #pragma unroll
    for (int s = 0; s < 4; ++s) {
        if (s < 3) {
            const int sn = s + 1;
            unsigned short* dst = &Ab[sn & 1][0] + w * 2048;
            #pragma unroll
            for (int t = 0; t < 4; ++t) {
                const char* p = (sn < 2) ? (hb + oL[t] + sn * 256)
                                         : (hb + oR[t] + (sn - 2) * 256);
                dma16((const unsigned short*)p, dst + t * 512);
            }
        }
        #pragma unroll
        for (int sub = 0; sub < 4; ++sub) {
            short8v bf[5];
            #pragma unroll
            for (int g = 0; g < 5; ++g) bf[g] = WTfv[boff[g] + (s * 4 + sub) * 64];
            #pragma unroll
            for (int rt = 0; rt < 4; ++rt) {
                const short8v af = *(const short8v*)&Ab[s & 1][(sub * 4 + rt) * 512 + lane * 8];
                #pragma unroll
                for (int g = 0; g < 5; ++g)
                    acc[rt][g] = __builtin_amdgcn_mfma_f32_16x16x32_bf16(
                        af, bf[g], acc[rt][g], 0, 0, 0);
            }
        }
        __syncthreads();
    }

    // ---- Epilogue: EW gates gathered from EWb[token] (bias included), child
    // c gathered direct.  C layout: col=lane&15, row=quad*4+reg.
    const int jl = w * 16 + col15;
    const int j  = jbase + jl;
    float hv[4][4], cv[4][4];
    #pragma unroll
    for (int rt = 0; rt < 4; ++rt) {
        #pragma unroll
        for (int reg = 0; reg < 4; ++reg) {
            const int rr = rt * 16 + quad * 4 + reg;
            const int grow = rowBase + rr;
            const int tok = tokens[(grow >> d) * NNODES + (n - 1) + (grow & (n - 1))];
            const unsigned short* ewp = EWb + (size_t)tok * NG + j;
            float cl, cr;
            if (LEAF) {
                const int b = grow >> 8, i = grow & 255;
                const int tokL = tokens[b * NNODES + 511 + 2 * i];
                const int tokR = tokens[b * NNODES + 512 + 2 * i];
                cl = bf2f(Cleaf[(size_t)tokL * HDIM + j]);
                cr = bf2f(Cleaf[(size_t)tokR * HDIM + j]);
            } else {
                cl = bf2f(csrc[(size_t)(2 * grow) * HDIM + j]);
                cr = bf2f(csrc[(size_t)(2 * grow + 1) * HDIM + j]);
            }
            const float gi  = acc[rt][0][reg] + bf2f(ewp[0]);
            const float gfl = acc[rt][1][reg] + bf2f(ewp[256]);
            const float gfr = acc[rt][2][reg] + bf2f(ewp[512]);
            const float go  = acc[rt][3][reg] + bf2f(ewp[768]);
            const float gu  = acc[rt][4][reg] + bf2f(ewp[1024]);
            const float ii = sigm(gi), fl = sigm(gfl), fr = sigm(gfr), oo = sigm(go);
            const float uu = tanh_fast(gu);
            const float c = ii * uu + fl * cl + fr * cr;
            const float h = oo * tanh_fast(c);
            cv[rt][reg] = c; hv[rt][reg] = h;
        }
    }

    // ---- Writeback via swizzled staging; Ab is dead past the last barrier.
    unsigned short* wb = &Ab[0][0];
    const int jchunk = jl >> 3, jpos = jl & 7;
    __syncthreads();
    #pragma unroll
    for (int rt = 0; rt < 4; ++rt) {
        #pragma unroll
        for (int reg = 0; reg < 4; ++reg) {
            const int rr = rt * 16 + quad * 4 + reg;
            const int roff = ((jchunk + 2 * quad) & 7) * 8 + jpos;
            wb[rr * 64 + roff]        = f2bf(hv[rt][reg]);
            wb[4096 + rr * 64 + roff] = f2bf(cv[rt][reg]);
        }
    }
    __syncthreads();
    #pragma unroll
    for (int k2 = 0; k2 < 4; ++k2) {
        const int c = tid + k2 * 256;
        const int arr = c >> 9, rr = (c >> 3) & 63, u = c & 7;
        const int ru = (u + 2 * ((rr >> 2) & 3)) & 7;
        const short8v v = *(const short8v*)(wb + (arr * 4096 + rr * 64 + ru * 8));
        unsigned short* dstp = (arr ? cdst : hdst) +
            (size_t)(rowBase + rr) * HDIM + jbase + u * 8;
        *(short8v*)dstp = v;
    }
}

// ---------------------------------------------------------------------------
// Tail levels d<=5 (latency regime): K=768 fold [hl|hr|x]@[Ul;Ur;Wx], BK=128
// (6 steps), bias hoisted, no epilogue EW gather on the serial chain.
// This is R4's measured-best tail kernel, unchanged.  (R5's persistent
// fused version regressed 5x: agent-scope barrier fences invalidated caches
// chip-wide -> 138 MB of refetch and 1 ms of spin.  Separate launches win.)
// ---------------------------------------------------------------------------
__global__ __launch_bounds__(256, 2) void level_fold(
    const unsigned short* __restrict__ WTf, const int* __restrict__ tokens,
    const unsigned short* __restrict__ embb,
    const unsigned short* __restrict__ hsrc, const unsigned short* __restrict__ csrc,
    const float* __restrict__ bias,
    unsigned short* __restrict__ hdst, unsigned short* __restrict__ cdst,
    float* __restrict__ out, const int d)
{
    const int n = 1 << d;

    __shared__ __align__(16) unsigned short Ab[2][8192];   // 32 KB: dbuf 64r x 128k

    const int tid  = threadIdx.x;
    const int lane = tid & 63;
    const int w    = tid >> 6;
    const int quad = lane >> 4, col15 = lane & 15;
    const int jt = blockIdx.x;
    const int rowBase = blockIdx.y * 64;
    const int jbase   = jt * 64;

    const uint32 inrow = (uint32)(w * 64 + quad * 16);
    uint32 oL[4], oR[4], oN[4];
    #pragma unroll
    for (int t = 0; t < 4; ++t) {
        const int srow = rowBase + t * 16 + col15;
        const int b = srow >> d, i = srow & (n - 1);
        oN[t] = (uint32)tokens[b * NNODES + (n - 1) + i] * 512u + inrow;
        oL[t] = (uint32)(2 * srow) * 512u + inrow;
        oR[t] = oL[t] + 512u;
    }
    const char* hb = (const char*)hsrc;
    const char* xb = (const char*)embb;

    const short8v* WTfv = (const short8v*)WTf;
    uint32 boff[5];
    #pragma unroll
    for (int g = 0; g < 5; ++g)
        boff[g] = ((g * 16 + jt * 4 + w) * 24) * 64 + lane;   // full K=768

    const int jl = w * 16 + col15;
    const int j  = jbase + jl;
    float bz[5];
    #pragma unroll
    for (int g = 0; g < 5; ++g) bz[g] = bias[g * 256 + j];

    float4v acc[4][5];
    #pragma unroll
    for (int rt = 0; rt < 4; ++rt)
        #pragma unroll
        for (int g = 0; g < 5; ++g)
            #pragma unroll
            for (int e = 0; e < 4; ++e) acc[rt][g][e] = 0.0f;

    {
        unsigned short* dst = &Ab[0][0] + w * 2048;
        #pragma unroll
        for (int t = 0; t < 4; ++t)
            dma16((const unsigned short*)(hb + oL[t]), dst + t * 512);
    }
    __syncthreads();

    #pragma unroll
    for (int s = 0; s < 6; ++s) {
        if (s < 5) {
            const int sn = s + 1;
            unsigned short* dst = &Ab[sn & 1][0] + w * 2048;
            #pragma unroll
            for (int t = 0; t < 4; ++t) {
                const char* p = (sn < 2) ? (hb + oL[t] + sn * 256)
                              : (sn < 4) ? (hb + oR[t] + (sn - 2) * 256)
                                         : (xb + oN[t] + (sn - 4) * 256);
                dma16((const unsigned short*)p, dst + t * 512);
            }
        }
        #pragma unroll
        for (int sub = 0; sub < 4; ++sub) {
            short8v bf[5];
            #pragma unroll
            for (int g = 0; g < 5; ++g) bf[g] = WTfv[boff[g] + (s * 4 + sub) * 64];
            #pragma unroll
            for (int rt = 0; rt < 4; ++rt) {
                const short8v af = *(const short8v*)&Ab[s & 1][(sub * 4 + rt) * 512 + lane * 8];
                #pragma unroll
                for (int g = 0; g < 5; ++g)
                    acc[rt][g] = __builtin_amdgcn_mfma_f32_16x16x32_bf16(
                        af, bf[g], acc[rt][g], 0, 0, 0);
            }
        }
        __syncthreads();
    }

    float hv[4][4], cv[4][4];
    #pragma unroll
    for (int rt = 0; rt < 4; ++rt) {
        #pragma unroll
        for (int reg = 0; reg < 4; ++reg) {
            const int rr = rt * 16 + quad * 4 + reg;
            const int grow = rowBase + rr;
            const float cl = bf2f(csrc[(size_t)(2 * grow) * HDIM + j]);
            const float cr = bf2f(csrc[(size_t)(2 * grow + 1) * HDIM + j]);
            const float gi  = acc[rt][0][reg] + bz[0];
            const float gfl = acc[rt][1][reg] + bz[1];
            const float gfr = acc[rt][2][reg] + bz[2];
            const float go  = acc[rt][3][reg] + bz[3];
            const float gu  = acc[rt][4][reg] + bz[4];
            const float ii = sigm(gi), fl = sigm(gfl), fr = sigm(gfr), oo = sigm(go);
            const float uu = tanh_fast(gu);
            const float c = ii * uu + fl * cl + fr * cr;
            const float h = oo * tanh_fast(c);
            cv[rt][reg] = c; hv[rt][reg] = h;
            if (d == 0) out[(size_t)grow * HDIM + j] = h;  // n==1 -> b=row
        }
    }
    if (d == 0) return;   // root level: nothing reads hdst/cdst

    unsigned short* wb = &Ab[0][0];
    const int jchunk = jl >> 3, jpos = jl & 7;
    #pragma unroll
    for (int rt = 0; rt < 4; ++rt) {
        #pragma unroll
        for (int reg = 0; reg < 4; ++reg) {
            const int rr = rt * 16 + quad * 4 + reg;
            const int roff = ((jchunk + 2 * quad) & 7) * 8 + jpos;
            wb[rr * 64 + roff]        = f2bf(hv[rt][reg]);
            wb[4096 + rr * 64 + roff] = f2bf(cv[rt][reg]);
        }
    }
    __syncthreads();
    #pragma unroll
    for (int k2 = 0; k2 < 4; ++k2) {
        const int c = tid + k2 * 256;
        const int arr = c >> 9, rr = (c >> 3) & 63, u = c & 7;
        const int ru = (u + 2 * ((rr >> 2) & 3)) & 7;
        const short8v v = *(const short8v*)(wb + (arr * 4096 + rr * 64 + ru * 8));
        unsigned short* dstp = (arr ? cdst : hdst) +
            (size_t)(rowBase + rr) * HDIM + jbase + u * 8;
        *(short8v*)dstp = v;
    }
}

// ---------------------------------------------------------------------------
extern "C" void kernel_launch(void* const* d_in, const int* in_sizes, int n_in,
                              void* d_out, int out_size, void* d_ws, size_t ws_size,
                              hipStream_t stream)
{
    const int*   tokens = (const int*)d_in[0];
    const float* emb    = (const float*)d_in[1];
    const float* Wx     = (const float*)d_in[2];
    const float* Ul     = (const float*)d_in[3];
    const float* Ur     = (const float*)d_in[4];
    const float* bias   = (const float*)d_in[5];
    float* out = (float*)d_out;

    // Workspace (bf16): EWb 5.24 | embb 1.05 | WTf 1.97 | Hleaf+Cleaf 2.1 |
    // hA,cA 2x8.4 | hB,cB 2x16.8  -> ~61 MB total.
    const size_t EW_ELEMS  = (size_t)VOCAB * NG;
    const size_t EMB_ELEMS = (size_t)VOCAB * HDIM;
    const size_t WTF_ELEMS = (size_t)80 * 24 * 64 * 8;
    const size_t LT_ELEMS  = (size_t)VOCAB * HDIM;        // each of Hleaf, Cleaf
    const size_t SLOT_A    = (size_t)16384 * HDIM;        // d=7,5,3,1 outputs
    const size_t SLOT_B    = (size_t)32768 * HDIM;        // d=8,6,4,2,0 outputs
    const size_t REQUIRED  = (EW_ELEMS + EMB_ELEMS + WTF_ELEMS + 2 * LT_ELEMS
                              + 2 * (SLOT_A + SLOT_B)) * 2;
    if (ws_size < REQUIRED || d_ws == nullptr) return;   // clean fail, not a fault

    char* ws = (char*)d_ws;
    unsigned short* EWb   = (unsigned short*)ws;
    unsigned short* embb  = EWb + EW_ELEMS;
    unsigned short* WTf   = embb + EMB_ELEMS;
    unsigned short* Hleaf = WTf + WTF_ELEMS;
    unsigned short* Cleaf = Hleaf + LT_ELEMS;
    unsigned short* hA    = Cleaf + LT_ELEMS;
    unsigned short* cA    = hA + SLOT_A;
    unsigned short* hB    = cA + SLOT_A;
    unsigned short* cB    = hB + SLOT_B;

    embb_kernel<<<dim3(256), 256, 0, stream>>>(emb, embb);
    prep_wtf<<<dim3(480), 256, 0, stream>>>(Ul, Ur, Wx, WTf);
    ewb_mfma<<<dim3(4, 32), 256, 0, stream>>>(WTf, embb, bias, EWb);
    leaftab_kernel<<<dim3(2048), 256, 0, stream>>>(EWb, Hleaf, Cleaf);

    // Big levels d=8..6: gather variant (K=512 + EW-gather epilogue).
    // Ping-pong: even d writes B-slot, odd d writes A-slot.
    level_gather<true><<<dim3(4, 512), 256, 0, stream>>>(
        WTf, tokens, EWb, Hleaf, Cleaf, nullptr, nullptr, hB, cB, 8);
    level_gather<false><<<dim3(4, 256), 256, 0, stream>>>(
        WTf, tokens, EWb, Hleaf, Cleaf, hB, cB, hA, cA, 7);
    level_gather<false><<<dim3(4, 128), 256, 0, stream>>>(
        WTf, tokens, EWb, Hleaf, Cleaf, hA, cA, hB, cB, 6);

    // Tail levels d=5..0: fold variant (K=768, latency-optimal), one launch
    // per level (R5's persistent fusion regressed 5x -- see level_fold note).
    for (int d = 5; d >= 0; --d) {
        const int NRB = 2 << d;
        const bool evenD = ((d & 1) == 0);
        const unsigned short* hs = evenD ? hA : hB;
        const unsigned short* cs = evenD ? cA : cB;
        unsigned short* hd = evenD ? hB : hA;
        unsigned short* cd = evenD ? cB : cA;
        level_fold<<<dim3(4, NRB), 256, 0, stream>>>(
            WTf, tokens, embb, hs, cs, bias, hd, cd, out, d);
    }
}

// Round 8
// 331.584 us; speedup vs baseline: 3.8970x; 1.0529x over previous
//
#include <hip/hip_runtime.h>
#include <hip/hip_bf16.h>
#include <math.h>

// Problem constants (from reference)
#define B_SZ   128
#define HDIM   256
#define NG     1280     // 5*H
#define NNODES 1023
#define VOCAB  2048

typedef unsigned int uint32;
typedef short  short8v  __attribute__((ext_vector_type(8)));   // 8 x bf16 (4 VGPR)
typedef float  float4v  __attribute__((ext_vector_type(4)));   // MFMA C/D frag

__device__ __forceinline__ float sigm(float x) {
    return 1.0f / (1.0f + __expf(-x));
}
__device__ __forceinline__ float tanh_fast(float x) {
    return 2.0f / (1.0f + __expf(-2.0f * x)) - 1.0f;
}
__device__ __forceinline__ float bf2f(unsigned short u) {
    return __uint_as_float(((uint32)u) << 16);
}
__device__ __forceinline__ unsigned short f2bf(float f) {
    uint32 x = __float_as_uint(f);
    uint32 r = (x + 0x7FFFu + ((x >> 16) & 1u)) >> 16;   // RNE
    return (unsigned short)r;
}

// Async 16B/lane global->LDS DMA. LDS dest = wave-uniform base + lane*16.
__device__ __forceinline__ void dma16(const unsigned short* gptr, unsigned short* lptr) {
    __builtin_amdgcn_global_load_lds(
        (const __attribute__((address_space(1))) void*)gptr,
        (__attribute__((address_space(3))) void*)lptr, 16, 0, 0);
}

// ---------------------------------------------------------------------------
// embb = bf16(emb) : 2048 x 256.  A-operand for the table builders + levels' x.
// ---------------------------------------------------------------------------
__global__ __launch_bounds__(256) void embb_kernel(
    const float* __restrict__ emb, unsigned short* __restrict__ embb)
{
    const int t = blockIdx.x * 256 + threadIdx.x;
    const float4 v0 = *(const float4*)(emb + (size_t)t * 8);
    const float4 v1 = *(const float4*)(emb + (size_t)t * 8 + 4);
    short8v o;
    o[0] = (short)f2bf(v0.x); o[1] = (short)f2bf(v0.y);
    o[2] = (short)f2bf(v0.z); o[3] = (short)f2bf(v0.w);
    o[4] = (short)f2bf(v1.x); o[5] = (short)f2bf(v1.y);
    o[6] = (short)f2bf(v1.z); o[7] = (short)f2bf(v1.w);
    *(short8v*)(embb + (size_t)t * 8) = o;
}

// ---------------------------------------------------------------------------
// WTf: fragment-ready bf16 repack of [Ul;Ur;Wx] (K=768, N=1280) for MFMA B.
// short8 index = (ng*24 + ks)*64 + lane ; lane = q*16 + c
//   holds B[k = ks*32 + q*8 + j][col = ng*16 + c],  j = 0..7
// Fold levels use all 24 ks; table builders use ks_base 0 (Ul), 8 (Ur),
// 16 (Wx) with 8 ks each (K=256).
// ---------------------------------------------------------------------------
__global__ __launch_bounds__(256) void prep_wtf(
    const float* __restrict__ Ul, const float* __restrict__ Ur,
    const float* __restrict__ Wx, unsigned short* __restrict__ WTf)
{
    const int t = blockIdx.x * 256 + threadIdx.x;   // 0..122879
    const int l = t & 63;
    const int q = l >> 4, c = l & 15;
    const int ks = (t >> 6) % 24;
    const int ng = t / (24 * 64);                    // 0..79
    const int col = ng * 16 + c;
    const int k = ks * 32 + q * 8;
    const float* src = (k < 256) ? (Ul + (size_t)k * NG + col)
                     : (k < 512) ? (Ur + (size_t)(k - 256) * NG + col)
                                 : (Wx + (size_t)(k - 512) * NG + col);
    short8v v;
    #pragma unroll
    for (int j = 0; j < 8; ++j) v[j] = (short)f2bf(src[(size_t)j * NG]);
    *(short8v*)(WTf + (size_t)t * 8) = v;
}

// ---------------------------------------------------------------------------
// gemm_tab: O[2048][1280] = bf16( A(2048x256) @ Wsec(256x1280) [+ bias] ).
// Wsec selected by ks_base (0 = Ul, 8 = Ur, 16 = Wx).  Generalization of the
// verified ewb_mfma (R18): builds EWb (embb,Wx,+bias), HUl (Hleaf,Ul),
// HUr (Hleaf,Ur).  R8 insight: d=8's GEMM A-rows are Hleaf[token] -- only
// 2048 distinct rows used ~32x each, so the whole 43-GFLOP d=8 GEMM is
// replaced by these 1.3-GFLOP-each per-token tables + a gather-add kernel.
// ---------------------------------------------------------------------------
__global__ __launch_bounds__(256, 2) void gemm_tab(
    const unsigned short* __restrict__ WTf, const unsigned short* __restrict__ A,
    const float* __restrict__ bias, unsigned short* __restrict__ O,
    const int ks_base)
{
    __shared__ __align__(16) unsigned short Ab[2][4096];   // 16 KB A dbuf
    __shared__ __align__(16) unsigned short wbE[20480];    // 40 KB: 5 gates x 64 rows x 64 cols

    const int tid  = threadIdx.x;
    const int lane = tid & 63;
    const int w    = tid >> 6;                  // 0..3 = col-tile
    const int quad = lane >> 4, col15 = lane & 15;
    const int jt = blockIdx.x;
    const int rowBase = blockIdx.y * 64;        // A row
    const int jbase   = jt * 64;

    const unsigned short* agp[2];
    unsigned short* ldst[2];
    #pragma unroll
    for (int t = 0; t < 2; ++t) {
        const int ch = 2 * w + t, sub = ch >> 2, rt = ch & 3;
        const int srow = rowBase + rt * 16 + col15;
        agp[t]  = A + (size_t)srow * HDIM + sub * 32 + quad * 8;
        ldst[t] = &Ab[0][0] + ch * 512;
    }

    const short8v* WTfv = (const short8v*)WTf;
    uint32 boff[5];
    #pragma unroll
    for (int g = 0; g < 5; ++g)
        boff[g] = (uint32)(((g * 16 + jt * 4 + w) * 24 + ks_base) * 64 + lane);

    float4v acc[4][5];
    #pragma unroll
    for (int rt = 0; rt < 4; ++rt)
        #pragma unroll
        for (int g = 0; g < 5; ++g)
            #pragma unroll
            for (int e = 0; e < 4; ++e) acc[rt][g][e] = 0.0f;

    dma16(agp[0], ldst[0]); dma16(agp[1], ldst[1]);
    __syncthreads();

    #pragma unroll
    for (int s = 0; s < 4; ++s) {
        if (s < 3) {
            dma16(agp[0] + (s + 1) * 64, ldst[0] + ((s + 1) & 1) * 4096);
            dma16(agp[1] + (s + 1) * 64, ldst[1] + ((s + 1) & 1) * 4096);
        }
        #pragma unroll
        for (int sub = 0; sub < 2; ++sub) {
            short8v bf[5];
            #pragma unroll
            for (int g = 0; g < 5; ++g) bf[g] = WTfv[boff[g] + (s * 2 + sub) * 64];
            #pragma unroll
            for (int rt = 0; rt < 4; ++rt) {
                const short8v af = *(const short8v*)&Ab[s & 1][(sub * 4 + rt) * 512 + lane * 8];
                #pragma unroll
                for (int g = 0; g < 5; ++g)
                    acc[rt][g] = __builtin_amdgcn_mfma_f32_16x16x32_bf16(
                        af, bf[g], acc[rt][g], 0, 0, 0);
            }
        }
        __syncthreads();
    }

    const int jl = w * 16 + col15;
    const int j  = jbase + jl;
    float bz[5];
    #pragma unroll
    for (int g = 0; g < 5; ++g) bz[g] = bias ? bias[g * 256 + j] : 0.0f;
    const int jchunk = jl >> 3, jpos = jl & 7;

    #pragma unroll
    for (int rt = 0; rt < 4; ++rt) {
        #pragma unroll
        for (int reg = 0; reg < 4; ++reg) {
            const int rr = rt * 16 + quad * 4 + reg;
            const int roff = ((jchunk + 2 * quad) & 7) * 8 + jpos;  // (rr>>2)&3==quad
            #pragma unroll
            for (int g = 0; g < 5; ++g)
                wbE[(g * 64 + rr) * 64 + roff] = f2bf(acc[rt][g][reg] + bz[g]);
        }
    }
    __syncthreads();

    #pragma unroll
    for (int k2 = 0; k2 < 10; ++k2) {
        const int c = tid + k2 * 256;                // 0..2559
        const int g = c >> 9, rr = (c >> 3) & 63, u = c & 7;
        const int ru = (u + 2 * ((rr >> 2) & 3)) & 7;
        const short8v v = *(const short8v*)&wbE[(g * 64 + rr) * 64 + ru * 8];
        *(short8v*)(O + (size_t)(rowBase + rr) * NG + g * 256 + jbase + u * 8) = v;
    }
}

// ---------------------------------------------------------------------------
// Leaf-as-table: leaf h/c depend ONLY on the token.
// ---------------------------------------------------------------------------
__global__ __launch_bounds__(256) void leaftab_kernel(
    const unsigned short* __restrict__ EWb,
    unsigned short* __restrict__ Hleaf, unsigned short* __restrict__ Cleaf)
{
    const int t = blockIdx.x * 256 + threadIdx.x;   // 0..524287
    const int tok = t >> 8, j = t & 255;
    const float gi = bf2f(EWb[(size_t)tok * NG + j]);
    const float go = bf2f(EWb[(size_t)tok * NG + 768 + j]);
    const float gu = bf2f(EWb[(size_t)tok * NG + 1024 + j]);
    const float c = sigm(gi) * tanh_fast(gu);
    const float h = sigm(go) * tanh_fast(c);
    Hleaf[t] = f2bf(h);
    Cleaf[t] = f2bf(c);
}

// ---------------------------------------------------------------------------
// leafcell: level d=8 WITHOUT a GEMM.  gates = HUl[tokL] + HUr[tokR] +
// EWb[tokN] (bias inside EWb) -> LSTM cell with cl/cr from Cleaf.
// 32768 rows x 32 col-octets; one thread = 8 h-cols of one row.
// All gathers are 16B/lane, rows shared across a 32-thread group ->
// coalesced 256B bursts from L2/L3-resident tables (~16 MB working set).
// ---------------------------------------------------------------------------
__global__ __launch_bounds__(256) void leafcell_kernel(
    const int* __restrict__ tokens,
    const unsigned short* __restrict__ HUl, const unsigned short* __restrict__ HUr,
    const unsigned short* __restrict__ EWb, const unsigned short* __restrict__ Cleaf,
    unsigned short* __restrict__ hdst, unsigned short* __restrict__ cdst)
{
    const int t = blockIdx.x * 256 + threadIdx.x;   // 0..1048575
    const int row = t >> 5;                          // 0..32767 = b*256 + i
    const int j   = (t & 31) * 8;                    // h-col octet
    const int b = row >> 8, i = row & 255;
    const int tokN = tokens[b * NNODES + 255 + i];
    const int tokL = tokens[b * NNODES + 511 + 2 * i];
    const int tokR = tokens[b * NNODES + 512 + 2 * i];

    const unsigned short* pl = HUl + (size_t)tokL * NG + j;
    const unsigned short* pr = HUr + (size_t)tokR * NG + j;
    const unsigned short* pn = EWb + (size_t)tokN * NG + j;

    float g5[5][8];
    #pragma unroll
    for (int g = 0; g < 5; ++g) {
        const short8v vl = *(const short8v*)(pl + g * 256);
        const short8v vr = *(const short8v*)(pr + g * 256);
        const short8v vn = *(const short8v*)(pn + g * 256);
        #pragma unroll
        for (int e = 0; e < 8; ++e)
            g5[g][e] = bf2f((unsigned short)vl[e]) + bf2f((unsigned short)vr[e])
                     + bf2f((unsigned short)vn[e]);
    }
    const short8v cl8 = *(const short8v*)(Cleaf + (size_t)tokL * HDIM + j);
    const short8v cr8 = *(const short8v*)(Cleaf + (size_t)tokR * HDIM + j);

    short8v ho, co;
    #pragma unroll
    for (int e = 0; e < 8; ++e) {
        const float ii = sigm(g5[0][e]), fl = sigm(g5[1][e]);
        const float fr = sigm(g5[2][e]), oo = sigm(g5[3][e]);
        const float uu = tanh_fast(g5[4][e]);
        const float c = ii * uu + fl * bf2f((unsigned short)cl8[e])
                                + fr * bf2f((unsigned short)cr8[e]);
        const float h = oo * tanh_fast(c);
        co[e] = (short)f2bf(c);
        ho[e] = (short)f2bf(h);
    }
    *(short8v*)(hdst + (size_t)row * HDIM + j) = ho;
    *(short8v*)(cdst + (size_t)row * HDIM + j) = co;
}

// ---------------------------------------------------------------------------
// Levels d=7..0: K=768 fold [hl|hr|x]@[Ul;Ur;Wx], BK=128 (6 steps), bias
// hoisted, no epilogue EW gather.  R7 algebra: fold beats gather by ~17.6 us
// combined at d=7/6 (gather's EWb reads thrash L2 while children stream);
// gather only won at d=8 where children were the L2-resident Hleaf -- and
// d=8 is now handled by leafcell (no GEMM at all).
// ---------------------------------------------------------------------------
__global__ __launch_bounds__(256, 2) void level_fold(
    const unsigned short* __restrict__ WTf, const int* __restrict__ tokens,
    const unsigned short* __restrict__ embb,
    const unsigned short* __restrict__ hsrc, const unsigned short* __restrict__ csrc,
    const float* __restrict__ bias,
    unsigned short* __restrict__ hdst, unsigned short* __restrict__ cdst,
    float* __restrict__ out, const int d)
{
    const int n = 1 << d;

    __shared__ __align__(16) unsigned short Ab[2][8192];   // 32 KB: dbuf 64r x 128k

    const int tid  = threadIdx.x;
    const int lane = tid & 63;
    const int w    = tid >> 6;
    const int quad = lane >> 4, col15 = lane & 15;
    const int jt = blockIdx.x;
    const int rowBase = blockIdx.y * 64;
    const int jbase   = jt * 64;

    const uint32 inrow = (uint32)(w * 64 + quad * 16);
    uint32 oL[4], oR[4], oN[4];
    #pragma unroll
    for (int t = 0; t < 4; ++t) {
        const int srow = rowBase + t * 16 + col15;
        const int b = srow >> d, i = srow & (n - 1);
        oN[t] = (uint32)tokens[b * NNODES + (n - 1) + i] * 512u + inrow;
        oL[t] = (uint32)(2 * srow) * 512u + inrow;
        oR[t] = oL[t] + 512u;
    }
    const char* hb = (const char*)hsrc;
    const char* xb = (const char*)embb;

    const short8v* WTfv = (const short8v*)WTf;
    uint32 boff[5];
    #pragma unroll
    for (int g = 0; g < 5; ++g)
        boff[g] = ((g * 16 + jt * 4 + w) * 24) * 64 + lane;   // full K=768

    const int jl = w * 16 + col15;
    const int j  = jbase + jl;
    float bz[5];
    #pragma unroll
    for (int g = 0; g < 5; ++g) bz[g] = bias[g * 256 + j];

    float4v acc[4][5];
    #pragma unroll
    for (int rt = 0; rt < 4; ++rt)
        #pragma unroll
        for (int g = 0; g < 5; ++g)
            #pragma unroll
            for (int e = 0; e < 4; ++e) acc[rt][g][e] = 0.0f;

    {
        unsigned short* dst = &Ab[0][0] + w * 2048;
        #pragma unroll
        for (int t = 0; t < 4; ++t)
            dma16((const unsigned short*)(hb + oL[t]), dst + t * 512);
    }
    __syncthreads();

    #pragma unroll
    for (int s = 0; s < 6; ++s) {
        if (s < 5) {
            const int sn = s + 1;
            unsigned short* dst = &Ab[sn & 1][0] + w * 2048;
            #pragma unroll
            for (int t = 0; t < 4; ++t) {
                const char* p = (sn < 2) ? (hb + oL[t] + sn * 256)
                              : (sn < 4) ? (hb + oR[t] + (sn - 2) * 256)
                                         : (xb + oN[t] + (sn - 4) * 256);
                dma16((const unsigned short*)p, dst + t * 512);
            }
        }
        #pragma unroll
        for (int sub = 0; sub < 4; ++sub) {
            short8v bf[5];
            #pragma unroll
            for (int g = 0; g < 5; ++g) bf[g] = WTfv[boff[g] + (s * 4 + sub) * 64];
            #pragma unroll
            for (int rt = 0; rt < 4; ++rt) {
                const short8v af = *(const short8v*)&Ab[s & 1][(sub * 4 + rt) * 512 + lane * 8];
                #pragma unroll
                for (int g = 0; g < 5; ++g)
                    acc[rt][g] = __builtin_amdgcn_mfma_f32_16x16x32_bf16(
                        af, bf[g], acc[rt][g], 0, 0, 0);
            }
        }
        __syncthreads();
    }

    float hv[4][4], cv[4][4];
    #pragma unroll
    for (int rt = 0; rt < 4; ++rt) {
        #pragma unroll
        for (int reg = 0; reg < 4; ++reg) {
            const int rr = rt * 16 + quad * 4 + reg;
            const int grow = rowBase + rr;
            const float cl = bf2f(csrc[(size_t)(2 * grow) * HDIM + j]);
            const float cr = bf2f(csrc[(size_t)(2 * grow + 1) * HDIM + j]);
            const float gi  = acc[rt][0][reg] + bz[0];
            const float gfl = acc[rt][1][reg] + bz[1];
            const float gfr = acc[rt][2][reg] + bz[2];
            const float go  = acc[rt][3][reg] + bz[3];
            const float gu  = acc[rt][4][reg] + bz[4];
            const float ii = sigm(gi), fl = sigm(gfl), fr = sigm(gfr), oo = sigm(go);
            const float uu = tanh_fast(gu);
            const float c = ii * uu + fl * cl + fr * cr;
            const float h = oo * tanh_fast(c);
            cv[rt][reg] = c; hv[rt][reg] = h;
            if (d == 0) out[(size_t)grow * HDIM + j] = h;  // n==1 -> b=row
        }
    }
    if (d == 0) return;   // root level: nothing reads hdst/cdst

    unsigned short* wb = &Ab[0][0];
    const int jchunk = jl >> 3, jpos = jl & 7;
    #pragma unroll
    for (int rt = 0; rt < 4; ++rt) {
        #pragma unroll
        for (int reg = 0; reg < 4; ++reg) {
            const int rr = rt * 16 + quad * 4 + reg;
            const int roff = ((jchunk + 2 * quad) & 7) * 8 + jpos;
            wb[rr * 64 + roff]        = f2bf(hv[rt][reg]);
            wb[4096 + rr * 64 + roff] = f2bf(cv[rt][reg]);
        }
    }
    __syncthreads();
    #pragma unroll
    for (int k2 = 0; k2 < 4; ++k2) {
        const int c = tid + k2 * 256;
        const int arr = c >> 9, rr = (c >> 3) & 63, u = c & 7;
        const int ru = (u + 2 * ((rr >> 2) & 3)) & 7;
        const short8v v = *(const short8v*)(wb + (arr * 4096 + rr * 64 + ru * 8));
        unsigned short* dstp = (arr ? cdst : hdst) +
            (size_t)(rowBase + rr) * HDIM + jbase + u * 8;
        *(short8v*)dstp = v;
    }
}

// ---------------------------------------------------------------------------
extern "C" void kernel_launch(void* const* d_in, const int* in_sizes, int n_in,
                              void* d_out, int out_size, void* d_ws, size_t ws_size,
                              hipStream_t stream)
{
    const int*   tokens = (const int*)d_in[0];
    const float* emb    = (const float*)d_in[1];
    const float* Wx     = (const float*)d_in[2];
    const float* Ul     = (const float*)d_in[3];
    const float* Ur     = (const float*)d_in[4];
    const float* bias   = (const float*)d_in[5];
    float* out = (float*)d_out;

    // Workspace (bf16): EWb 5.24 | HUl 5.24 | HUr 5.24 | embb 1.05 | WTf 1.97
    // | Hleaf+Cleaf 2.1 | hA,cA 2x8.4 | hB,cB 2x16.8  -> ~70 MB total
    // (109 MB passed historically; headroom confirmed).
    const size_t EW_ELEMS  = (size_t)VOCAB * NG;          // also HUl/HUr size
    const size_t EMB_ELEMS = (size_t)VOCAB * HDIM;
    const size_t WTF_ELEMS = (size_t)80 * 24 * 64 * 8;
    const size_t LT_ELEMS  = (size_t)VOCAB * HDIM;        // each of Hleaf, Cleaf
    const size_t SLOT_A    = (size_t)16384 * HDIM;        // d=7,5,3,1 outputs
    const size_t SLOT_B    = (size_t)32768 * HDIM;        // d=8,6,4,2,0 outputs
    const size_t REQUIRED  = (3 * EW_ELEMS + EMB_ELEMS + WTF_ELEMS + 2 * LT_ELEMS
                              + 2 * (SLOT_A + SLOT_B)) * 2;
    if (ws_size < REQUIRED || d_ws == nullptr) return;   // clean fail, not a fault

    char* ws = (char*)d_ws;
    unsigned short* EWb   = (unsigned short*)ws;
    unsigned short* HUl   = EWb + EW_ELEMS;
    unsigned short* HUr   = HUl + EW_ELEMS;
    unsigned short* embb  = HUr + EW_ELEMS;
    unsigned short* WTf   = embb + EMB_ELEMS;
    unsigned short* Hleaf = WTf + WTF_ELEMS;
    unsigned short* Cleaf = Hleaf + LT_ELEMS;
    unsigned short* hA    = Cleaf + LT_ELEMS;
    unsigned short* cA    = hA + SLOT_A;
    unsigned short* hB    = cA + SLOT_A;
    unsigned short* cB    = hB + SLOT_B;

    embb_kernel<<<dim3(256), 256, 0, stream>>>(emb, embb);
    prep_wtf<<<dim3(480), 256, 0, stream>>>(Ul, Ur, Wx, WTf);
    gemm_tab<<<dim3(4, 32), 256, 0, stream>>>(WTf, embb, bias, EWb, 16);   // x@Wx + b
    leaftab_kernel<<<dim3(2048), 256, 0, stream>>>(EWb, Hleaf, Cleaf);
    gemm_tab<<<dim3(4, 32), 256, 0, stream>>>(WTf, Hleaf, nullptr, HUl, 0); // Hleaf@Ul
    gemm_tab<<<dim3(4, 32), 256, 0, stream>>>(WTf, Hleaf, nullptr, HUr, 8); // Hleaf@Ur

    // Level d=8: pure table gather + cell (no GEMM).  Writes B-slot.
    leafcell_kernel<<<dim3(4096), 256, 0, stream>>>(
        tokens, HUl, HUr, EWb, Cleaf, hB, cB);

    // Levels d=7..0: fold variant, one launch per level.
    for (int d = 7; d >= 0; --d) {
        const int NRB = 2 << d;
        const bool evenD = ((d & 1) == 0);
        const unsigned short* hs = evenD ? hA : hB;
        const unsigned short* cs = evenD ? cA : cB;
        unsigned short* hd = evenD ? hB : hA;
        unsigned short* cd = evenD ? cB : cA;
        level_fold<<<dim3(4, NRB), 256, 0, stream>>>(
            WTf, tokens, embb, hs, cs, bias, hd, cd, out, d);
    }
}

// Round 9
// 324.855 us; speedup vs baseline: 3.9778x; 1.0207x over previous
//
#include <hip/hip_runtime.h>
#include <hip/hip_bf16.h>
#include <math.h>

// Problem constants (from reference)
#define B_SZ   128
#define HDIM   256
#define NG     1280     // 5*H
#define NNODES 1023
#define VOCAB  2048

typedef unsigned int uint32;
typedef short  short8v  __attribute__((ext_vector_type(8)));   // 8 x bf16 (4 VGPR)
typedef float  float4v  __attribute__((ext_vector_type(4)));   // MFMA C/D frag

__device__ __forceinline__ float sigm(float x) {
    return 1.0f / (1.0f + __expf(-x));
}
__device__ __forceinline__ float tanh_fast(float x) {
    return 2.0f / (1.0f + __expf(-2.0f * x)) - 1.0f;
}
__device__ __forceinline__ float bf2f(unsigned short u) {
    return __uint_as_float(((uint32)u) << 16);
}
__device__ __forceinline__ unsigned short f2bf(float f) {
    uint32 x = __float_as_uint(f);
    uint32 r = (x + 0x7FFFu + ((x >> 16) & 1u)) >> 16;   // RNE
    return (unsigned short)r;
}

// Async 16B/lane global->LDS DMA. LDS dest = wave-uniform base + lane*16.
__device__ __forceinline__ void dma16(const unsigned short* gptr, unsigned short* lptr) {
    __builtin_amdgcn_global_load_lds(
        (const __attribute__((address_space(1))) void*)gptr,
        (__attribute__((address_space(3))) void*)lptr, 16, 0, 0);
}

// ---------------------------------------------------------------------------
// embb = bf16(emb) : 2048 x 256.  A-operand for the table builders + levels' x.
// ---------------------------------------------------------------------------
__global__ __launch_bounds__(256) void embb_kernel(
    const float* __restrict__ emb, unsigned short* __restrict__ embb)
{
    const int t = blockIdx.x * 256 + threadIdx.x;
    const float4 v0 = *(const float4*)(emb + (size_t)t * 8);
    const float4 v1 = *(const float4*)(emb + (size_t)t * 8 + 4);
    short8v o;
    o[0] = (short)f2bf(v0.x); o[1] = (short)f2bf(v0.y);
    o[2] = (short)f2bf(v0.z); o[3] = (short)f2bf(v0.w);
    o[4] = (short)f2bf(v1.x); o[5] = (short)f2bf(v1.y);
    o[6] = (short)f2bf(v1.z); o[7] = (short)f2bf(v1.w);
    *(short8v*)(embb + (size_t)t * 8) = o;
}

// ---------------------------------------------------------------------------
// WTf: fragment-ready bf16 repack of [Ul;Ur;Wx] (K=768, N=1280) for MFMA B.
// short8 index = (ng*24 + ks)*64 + lane ; lane = q*16 + c
//   holds B[k = ks*32 + q*8 + j][col = ng*16 + c],  j = 0..7
// Fold levels use all 24 ks; table builders use ks_base 0 (Ul), 8 (Ur),
// 16 (Wx) with 8 ks each (K=256).
// ---------------------------------------------------------------------------
__global__ __launch_bounds__(256) void prep_wtf(
    const float* __restrict__ Ul, const float* __restrict__ Ur,
    const float* __restrict__ Wx, unsigned short* __restrict__ WTf)
{
    const int t = blockIdx.x * 256 + threadIdx.x;   // 0..122879
    const int l = t & 63;
    const int q = l >> 4, c = l & 15;
    const int ks = (t >> 6) % 24;
    const int ng = t / (24 * 64);                    // 0..79
    const int col = ng * 16 + c;
    const int k = ks * 32 + q * 8;
    const float* src = (k < 256) ? (Ul + (size_t)k * NG + col)
                     : (k < 512) ? (Ur + (size_t)(k - 256) * NG + col)
                                 : (Wx + (size_t)(k - 512) * NG + col);
    short8v v;
    #pragma unroll
    for (int j = 0; j < 8; ++j) v[j] = (short)f2bf(src[(size_t)j * NG]);
    *(short8v*)(WTf + (size_t)t * 8) = v;
}

// ---------------------------------------------------------------------------
// gemm_tab: O[2048][1280] = bf16( A(2048x256) @ Wsec(256x1280) [+ bias] ).
// Wsec = ks_base0 + 8*blockIdx.z (0=Ul, 8=Ur, 16=Wx); O = z ? O1 : O0 --
// the two HU builds run as ONE launch with gridDim.z=2 (R9: saves a serial
// dispatch + doubles CU fill).  TAB=true additionally computes the leaf
// h/c tables in-epilogue from acc (R9: absorbs the leaftab kernel; gates
// here are pre-bf16-rounding, slightly MORE accurate than the old path).
// ---------------------------------------------------------------------------
template <bool TAB>
__global__ __launch_bounds__(256, 2) void gemm_tab(
    const unsigned short* __restrict__ WTf, const unsigned short* __restrict__ A,
    const float* __restrict__ bias, unsigned short* __restrict__ O0,
    unsigned short* __restrict__ O1,
    unsigned short* __restrict__ Hleaf, unsigned short* __restrict__ Cleaf,
    const int ks_base0)
{
    __shared__ __align__(16) unsigned short Ab[2][4096];   // 16 KB A dbuf
    __shared__ __align__(16) unsigned short wbE[20480];    // 40 KB: 5 gates x 64 rows x 64 cols

    const int tid  = threadIdx.x;
    const int lane = tid & 63;
    const int w    = tid >> 6;                  // 0..3 = col-tile
    const int quad = lane >> 4, col15 = lane & 15;
    const int jt = blockIdx.x;
    const int rowBase = blockIdx.y * 64;        // A row
    const int jbase   = jt * 64;
    const int ks_base = ks_base0 + (int)blockIdx.z * 8;
    unsigned short* O = blockIdx.z ? O1 : O0;

    const unsigned short* agp[2];
    unsigned short* ldst[2];
    #pragma unroll
    for (int t = 0; t < 2; ++t) {
        const int ch = 2 * w + t, sub = ch >> 2, rt = ch & 3;
        const int srow = rowBase + rt * 16 + col15;
        agp[t]  = A + (size_t)srow * HDIM + sub * 32 + quad * 8;
        ldst[t] = &Ab[0][0] + ch * 512;
    }

    const short8v* WTfv = (const short8v*)WTf;
    uint32 boff[5];
    #pragma unroll
    for (int g = 0; g < 5; ++g)
        boff[g] = (uint32)(((g * 16 + jt * 4 + w) * 24 + ks_base) * 64 + lane);

    float4v acc[4][5];
    #pragma unroll
    for (int rt = 0; rt < 4; ++rt)
        #pragma unroll
        for (int g = 0; g < 5; ++g)
            #pragma unroll
            for (int e = 0; e < 4; ++e) acc[rt][g][e] = 0.0f;

    dma16(agp[0], ldst[0]); dma16(agp[1], ldst[1]);
    __syncthreads();

    #pragma unroll
    for (int s = 0; s < 4; ++s) {
        if (s < 3) {
            dma16(agp[0] + (s + 1) * 64, ldst[0] + ((s + 1) & 1) * 4096);
            dma16(agp[1] + (s + 1) * 64, ldst[1] + ((s + 1) & 1) * 4096);
        }
        #pragma unroll
        for (int sub = 0; sub < 2; ++sub) {
            short8v bf[5];
            #pragma unroll
            for (int g = 0; g < 5; ++g) bf[g] = WTfv[boff[g] + (s * 2 + sub) * 64];
            #pragma unroll
            for (int rt = 0; rt < 4; ++rt) {
                const short8v af = *(const short8v*)&Ab[s & 1][(sub * 4 + rt) * 512 + lane * 8];
                #pragma unroll
                for (int g = 0; g < 5; ++g)
                    acc[rt][g] = __builtin_amdgcn_mfma_f32_16x16x32_bf16(
                        af, bf[g], acc[rt][g], 0, 0, 0);
            }
        }
        __syncthreads();
    }

    const int jl = w * 16 + col15;
    const int j  = jbase + jl;
    float bz[5];
    #pragma unroll
    for (int g = 0; g < 5; ++g) bz[g] = bias ? bias[g * 256 + j] : 0.0f;
    const int jchunk = jl >> 3, jpos = jl & 7;

    if (TAB) {
        // Leaf h/c tables directly from acc (gates for this 64x64 tile are
        // complete here: gi=g0, go=g3, gu=g4).
        #pragma unroll
        for (int rt = 0; rt < 4; ++rt) {
            #pragma unroll
            for (int reg = 0; reg < 4; ++reg) {
                const int rr = rt * 16 + quad * 4 + reg;
                const float gi = acc[rt][0][reg] + bz[0];
                const float go = acc[rt][3][reg] + bz[3];
                const float gu = acc[rt][4][reg] + bz[4];
                const float c = sigm(gi) * tanh_fast(gu);
                const float h = sigm(go) * tanh_fast(c);
                Hleaf[(size_t)(rowBase + rr) * HDIM + j] = f2bf(h);
                Cleaf[(size_t)(rowBase + rr) * HDIM + j] = f2bf(c);
            }
        }
    }

    #pragma unroll
    for (int rt = 0; rt < 4; ++rt) {
        #pragma unroll
        for (int reg = 0; reg < 4; ++reg) {
            const int rr = rt * 16 + quad * 4 + reg;
            const int roff = ((jchunk + 2 * quad) & 7) * 8 + jpos;  // (rr>>2)&3==quad
            #pragma unroll
            for (int g = 0; g < 5; ++g)
                wbE[(g * 64 + rr) * 64 + roff] = f2bf(acc[rt][g][reg] + bz[g]);
        }
    }
    __syncthreads();

    #pragma unroll
    for (int k2 = 0; k2 < 10; ++k2) {
        const int c = tid + k2 * 256;                // 0..2559
        const int g = c >> 9, rr = (c >> 3) & 63, u = c & 7;
        const int ru = (u + 2 * ((rr >> 2) & 3)) & 7;
        const short8v v = *(const short8v*)&wbE[(g * 64 + rr) * 64 + ru * 8];
        *(short8v*)(O + (size_t)(rowBase + rr) * NG + g * 256 + jbase + u * 8) = v;
    }
}

// ---------------------------------------------------------------------------
// leafcell: level d=8 WITHOUT a GEMM.  gates = HUl[tokL] + HUr[tokR] +
// EWb[tokN] (bias inside EWb) -> LSTM cell with cl/cr from Cleaf.
// ---------------------------------------------------------------------------
__global__ __launch_bounds__(256) void leafcell_kernel(
    const int* __restrict__ tokens,
    const unsigned short* __restrict__ HUl, const unsigned short* __restrict__ HUr,
    const unsigned short* __restrict__ EWb, const unsigned short* __restrict__ Cleaf,
    unsigned short* __restrict__ hdst, unsigned short* __restrict__ cdst)
{
    const int t = blockIdx.x * 256 + threadIdx.x;   // 0..1048575
    const int row = t >> 5;                          // 0..32767 = b*256 + i
    const int j   = (t & 31) * 8;                    // h-col octet
    const int b = row >> 8, i = row & 255;
    const int tokN = tokens[b * NNODES + 255 + i];
    const int tokL = tokens[b * NNODES + 511 + 2 * i];
    const int tokR = tokens[b * NNODES + 512 + 2 * i];

    const unsigned short* pl = HUl + (size_t)tokL * NG + j;
    const unsigned short* pr = HUr + (size_t)tokR * NG + j;
    const unsigned short* pn = EWb + (size_t)tokN * NG + j;

    float g5[5][8];
    #pragma unroll
    for (int g = 0; g < 5; ++g) {
        const short8v vl = *(const short8v*)(pl + g * 256);
        const short8v vr = *(const short8v*)(pr + g * 256);
        const short8v vn = *(const short8v*)(pn + g * 256);
        #pragma unroll
        for (int e = 0; e < 8; ++e)
            g5[g][e] = bf2f((unsigned short)vl[e]) + bf2f((unsigned short)vr[e])
                     + bf2f((unsigned short)vn[e]);
    }
    const short8v cl8 = *(const short8v*)(Cleaf + (size_t)tokL * HDIM + j);
    const short8v cr8 = *(const short8v*)(Cleaf + (size_t)tokR * HDIM + j);

    short8v ho, co;
    #pragma unroll
    for (int e = 0; e < 8; ++e) {
        const float ii = sigm(g5[0][e]), fl = sigm(g5[1][e]);
        const float fr = sigm(g5[2][e]), oo = sigm(g5[3][e]);
        const float uu = tanh_fast(g5[4][e]);
        const float c = ii * uu + fl * bf2f((unsigned short)cl8[e])
                                + fr * bf2f((unsigned short)cr8[e]);
        const float h = oo * tanh_fast(c);
        co[e] = (short)f2bf(c);
        ho[e] = (short)f2bf(h);
    }
    *(short8v*)(hdst + (size_t)row * HDIM + j) = ho;
    *(short8v*)(cdst + (size_t)row * HDIM + j) = co;
}

// ---------------------------------------------------------------------------
// Levels d=7..0: K=768 fold [hl|hr|x]@[Ul;Ur;Wx], BK=128 (6 steps), bias
// hoisted, no epilogue EW gather.
// R9 grid fix: grid is now (rowTile, jt) -- ROWS in x, jt in y.  Previously
// jt was fastest, so the 4 blocks sharing the same 128 child h/c rows were
// consecutive in linear id -> round-robined onto 4 DIFFERENT XCDs -> ~4x
// duplicate HBM fetch of the child streams (d=7 FETCH 52 MB vs ~35 ideal).
// With rows fastest, jt-mates differ by NRB (mult of 8) in linear id ->
// SAME XCD -> children shared in that XCD's L2.
// ---------------------------------------------------------------------------
__global__ __launch_bounds__(256, 2) void level_fold(
    const unsigned short* __restrict__ WTf, const int* __restrict__ tokens,
    const unsigned short* __restrict__ embb,
    const unsigned short* __restrict__ hsrc, const unsigned short* __restrict__ csrc,
    const float* __restrict__ bias,
    unsigned short* __restrict__ hdst, unsigned short* __restrict__ cdst,
    float* __restrict__ out, const int d)
{
    const int n = 1 << d;

    __shared__ __align__(16) unsigned short Ab[2][8192];   // 32 KB: dbuf 64r x 128k

    const int tid  = threadIdx.x;
    const int lane = tid & 63;
    const int w    = tid >> 6;
    const int quad = lane >> 4, col15 = lane & 15;
    const int jt = blockIdx.y;                  // 0..3 (slow dim now)
    const int rowBase = blockIdx.x * 64;        // rows fastest
    const int jbase   = jt * 64;

    const uint32 inrow = (uint32)(w * 64 + quad * 16);
    uint32 oL[4], oR[4], oN[4];
    #pragma unroll
    for (int t = 0; t < 4; ++t) {
        const int srow = rowBase + t * 16 + col15;
        const int b = srow >> d, i = srow & (n - 1);
        oN[t] = (uint32)tokens[b * NNODES + (n - 1) + i] * 512u + inrow;
        oL[t] = (uint32)(2 * srow) * 512u + inrow;
        oR[t] = oL[t] + 512u;
    }
    const char* hb = (const char*)hsrc;
    const char* xb = (const char*)embb;

    const short8v* WTfv = (const short8v*)WTf;
    uint32 boff[5];
    #pragma unroll
    for (int g = 0; g < 5; ++g)
        boff[g] = ((g * 16 + jt * 4 + w) * 24) * 64 + lane;   // full K=768

    const int jl = w * 16 + col15;
    const int j  = jbase + jl;
    float bz[5];
    #pragma unroll
    for (int g = 0; g < 5; ++g) bz[g] = bias[g * 256 + j];

    float4v acc[4][5];
    #pragma unroll
    for (int rt = 0; rt < 4; ++rt)
        #pragma unroll
        for (int g = 0; g < 5; ++g)
            #pragma unroll
            for (int e = 0; e < 4; ++e) acc[rt][g][e] = 0.0f;

    {
        unsigned short* dst = &Ab[0][0] + w * 2048;
        #pragma unroll
        for (int t = 0; t < 4; ++t)
            dma16((const unsigned short*)(hb + oL[t]), dst + t * 512);
    }
    __syncthreads();

    #pragma unroll
    for (int s = 0; s < 6; ++s) {
        if (s < 5) {
            const int sn = s + 1;
            unsigned short* dst = &Ab[sn & 1][0] + w * 2048;
            #pragma unroll
            for (int t = 0; t < 4; ++t) {
                const char* p = (sn < 2) ? (hb + oL[t] + sn * 256)
                              : (sn < 4) ? (hb + oR[t] + (sn - 2) * 256)
                                         : (xb + oN[t] + (sn - 4) * 256);
                dma16((const unsigned short*)p, dst + t * 512);
            }
        }
        #pragma unroll
        for (int sub = 0; sub < 4; ++sub) {
            short8v bf[5];
            #pragma unroll
            for (int g = 0; g < 5; ++g) bf[g] = WTfv[boff[g] + (s * 4 + sub) * 64];
            #pragma unroll
            for (int rt = 0; rt < 4; ++rt) {
                const short8v af = *(const short8v*)&Ab[s & 1][(sub * 4 + rt) * 512 + lane * 8];
                #pragma unroll
                for (int g = 0; g < 5; ++g)
                    acc[rt][g] = __builtin_amdgcn_mfma_f32_16x16x32_bf16(
                        af, bf[g], acc[rt][g], 0, 0, 0);
            }
        }
        __syncthreads();
    }

    float hv[4][4], cv[4][4];
    #pragma unroll
    for (int rt = 0; rt < 4; ++rt) {
        #pragma unroll
        for (int reg = 0; reg < 4; ++reg) {
            const int rr = rt * 16 + quad * 4 + reg;
            const int grow = rowBase + rr;
            const float cl = bf2f(csrc[(size_t)(2 * grow) * HDIM + j]);
            const float cr = bf2f(csrc[(size_t)(2 * grow + 1) * HDIM + j]);
            const float gi  = acc[rt][0][reg] + bz[0];
            const float gfl = acc[rt][1][reg] + bz[1];
            const float gfr = acc[rt][2][reg] + bz[2];
            const float go  = acc[rt][3][reg] + bz[3];
            const float gu  = acc[rt][4][reg] + bz[4];
            const float ii = sigm(gi), fl = sigm(gfl), fr = sigm(gfr), oo = sigm(go);
            const float uu = tanh_fast(gu);
            const float c = ii * uu + fl * cl + fr * cr;
            const float h = oo * tanh_fast(c);
            cv[rt][reg] = c; hv[rt][reg] = h;
            if (d == 0) out[(size_t)grow * HDIM + j] = h;  // n==1 -> b=row
        }
    }
    if (d == 0) return;   // root level: nothing reads hdst/cdst

    unsigned short* wb = &Ab[0][0];
    const int jchunk = jl >> 3, jpos = jl & 7;
    #pragma unroll
    for (int rt = 0; rt < 4; ++rt) {
        #pragma unroll
        for (int reg = 0; reg < 4; ++reg) {
            const int rr = rt * 16 + quad * 4 + reg;
            const int roff = ((jchunk + 2 * quad) & 7) * 8 + jpos;
            wb[rr * 64 + roff]        = f2bf(hv[rt][reg]);
            wb[4096 + rr * 64 + roff] = f2bf(cv[rt][reg]);
        }
    }
    __syncthreads();
    #pragma unroll
    for (int k2 = 0; k2 < 4; ++k2) {
        const int c = tid + k2 * 256;
        const int arr = c >> 9, rr = (c >> 3) & 63, u = c & 7;
        const int ru = (u + 2 * ((rr >> 2) & 3)) & 7;
        const short8v v = *(const short8v*)(wb + (arr * 4096 + rr * 64 + ru * 8));
        unsigned short* dstp = (arr ? cdst : hdst) +
            (size_t)(rowBase + rr) * HDIM + jbase + u * 8;
        *(short8v*)dstp = v;
    }
}

// ---------------------------------------------------------------------------
extern "C" void kernel_launch(void* const* d_in, const int* in_sizes, int n_in,
                              void* d_out, int out_size, void* d_ws, size_t ws_size,
                              hipStream_t stream)
{
    const int*   tokens = (const int*)d_in[0];
    const float* emb    = (const float*)d_in[1];
    const float* Wx     = (const float*)d_in[2];
    const float* Ul     = (const float*)d_in[3];
    const float* Ur     = (const float*)d_in[4];
    const float* bias   = (const float*)d_in[5];
    float* out = (float*)d_out;

    // Workspace (bf16): EWb 5.24 | HUl 5.24 | HUr 5.24 | embb 1.05 | WTf 1.97
    // | Hleaf+Cleaf 2.1 | hA,cA 2x8.4 | hB,cB 2x16.8  -> ~70 MB total.
    const size_t EW_ELEMS  = (size_t)VOCAB * NG;          // also HUl/HUr size
    const size_t EMB_ELEMS = (size_t)VOCAB * HDIM;
    const size_t WTF_ELEMS = (size_t)80 * 24 * 64 * 8;
    const size_t LT_ELEMS  = (size_t)VOCAB * HDIM;        // each of Hleaf, Cleaf
    const size_t SLOT_A    = (size_t)16384 * HDIM;        // d=7,5,3,1 outputs
    const size_t SLOT_B    = (size_t)32768 * HDIM;        // d=8,6,4,2,0 outputs
    const size_t REQUIRED  = (3 * EW_ELEMS + EMB_ELEMS + WTF_ELEMS + 2 * LT_ELEMS
                              + 2 * (SLOT_A + SLOT_B)) * 2;
    if (ws_size < REQUIRED || d_ws == nullptr) return;   // clean fail, not a fault

    char* ws = (char*)d_ws;
    unsigned short* EWb   = (unsigned short*)ws;
    unsigned short* HUl   = EWb + EW_ELEMS;
    unsigned short* HUr   = HUl + EW_ELEMS;
    unsigned short* embb  = HUr + EW_ELEMS;
    unsigned short* WTf   = embb + EMB_ELEMS;
    unsigned short* Hleaf = WTf + WTF_ELEMS;
    unsigned short* Cleaf = Hleaf + LT_ELEMS;
    unsigned short* hA    = Cleaf + LT_ELEMS;
    unsigned short* cA    = hA + SLOT_A;
    unsigned short* hB    = cA + SLOT_A;
    unsigned short* cB    = hB + SLOT_B;

    embb_kernel<<<dim3(256), 256, 0, stream>>>(emb, embb);
    prep_wtf<<<dim3(480), 256, 0, stream>>>(Ul, Ur, Wx, WTf);
    // EWb = x@Wx + b, with leaf h/c tables fused into the epilogue.
    gemm_tab<true><<<dim3(4, 32, 1), 256, 0, stream>>>(
        WTf, embb, bias, EWb, nullptr, Hleaf, Cleaf, 16);
    // HUl = Hleaf@Ul and HUr = Hleaf@Ur in ONE launch (z selects section).
    gemm_tab<false><<<dim3(4, 32, 2), 256, 0, stream>>>(
        WTf, Hleaf, nullptr, HUl, HUr, nullptr, nullptr, 0);

    // Level d=8: pure table gather + cell (no GEMM).  Writes B-slot.
    leafcell_kernel<<<dim3(4096), 256, 0, stream>>>(
        tokens, HUl, HUr, EWb, Cleaf, hB, cB);

    // Levels d=7..0: fold variant; rows in grid.x (jt-mates co-XCD).
    for (int d = 7; d >= 0; --d) {
        const int NRB = 2 << d;
        const bool evenD = ((d & 1) == 0);
        const unsigned short* hs = evenD ? hA : hB;
        const unsigned short* cs = evenD ? cA : cB;
        unsigned short* hd = evenD ? hB : hA;
        unsigned short* cd = evenD ? cB : cA;
        level_fold<<<dim3(NRB, 4), 256, 0, stream>>>(
            WTf, tokens, embb, hs, cs, bias, hd, cd, out, d);
    }
}